// Round 8
// baseline (886.751 us; speedup 1.0000x reference)
//
#include <hip/hip_runtime.h>
#include <math.h>

namespace {

constexpr int B_ = 4, L_ = 1024, H_ = 1024, NH_ = 16, HD_ = 64, ND_ = 1024, ITERS_ = 4;

typedef unsigned short u16;
typedef __attribute__((ext_vector_type(8))) short short8;
typedef __attribute__((ext_vector_type(4))) float f32x4;

__device__ inline u16 f2bf(float f) {
  unsigned u = __builtin_bit_cast(unsigned, f);
  u += 0x7FFFu + ((u >> 16) & 1u);
  return (u16)(u >> 16);
}
__device__ inline float bf2f(u16 v) {
  unsigned u = ((unsigned)v) << 16;
  return __builtin_bit_cast(float, u);
}

__device__ inline void gl_lds16(const u16* g, u16* l) {
  __builtin_amdgcn_global_load_lds((const __attribute__((address_space(1))) void*)g,
                                   (__attribute__((address_space(3))) void*)l, 16, 0, 0);
}

// ---------- prep: 5 f2bf conversions + nodes copy ----------
__global__ void k_prep(const float* __restrict__ data, const float* __restrict__ rwq,
                       const float* __restrict__ rwk, const float* __restrict__ rwv,
                       const float* __restrict__ rwo,
                       u16* __restrict__ embs_bf, u16* __restrict__ wq_bf,
                       u16* __restrict__ wk_bf, u16* __restrict__ wv_bf,
                       u16* __restrict__ wo_bf, float* __restrict__ nodes) {
  int i = blockIdx.x * 256 + threadIdx.x;
  int which = blockIdx.y;
  if (which == 5) {
    reinterpret_cast<float4*>(nodes)[i] = reinterpret_cast<const float4*>(data)[i];
    return;
  }
  const float* src;
  u16* dst;
  switch (which) {
    case 0: src = data; dst = embs_bf; break;
    case 1: src = rwq; dst = wq_bf; break;
    case 2: src = rwk; dst = wk_bf; break;
    case 3: src = rwv; dst = wv_bf; break;
    default: src = rwo; dst = wo_bf; break;
  }
  float4 v = reinterpret_cast<const float4*>(src)[i];
  ushort4 o;
  o.x = f2bf(v.x); o.y = f2bf(v.y); o.z = f2bf(v.z); o.w = f2bf(v.w);
  reinterpret_cast<ushort4*>(dst)[i] = o;
}

// ---------- relay init ----------
__global__ void k_relay_part(const float* __restrict__ data, float* __restrict__ part) {
  int b = blockIdx.z, chunk = blockIdx.y;
  int c = blockIdx.x * 256 + threadIdx.x;
  const float* p = data + ((size_t)b * L_ + chunk * 128) * H_ + c;
  float acc = 0.f;
  for (int l = 0; l < 128; ++l) acc += p[(size_t)l * H_];
  part[((size_t)b * 8 + chunk) * H_ + c] = acc;
}
__global__ void k_relay_reduce(const float* __restrict__ part, float* __restrict__ relay) {
  int i = blockIdx.x * 256 + threadIdx.x;
  int b = i >> 10, c = i & 1023;
  float acc = 0.f;
  for (int j = 0; j < 8; ++j) acc += part[((size_t)b * 8 + j) * H_ + c];
  relay[i] = acc * (1.f / (float)L_);
}

// ---------- LayerNorm rows of nodes [B,L,H]; fused pad-row zeroing ----------
__global__ __launch_bounds__(256) void k_layernorm_bf(float* __restrict__ nodes,
                                                      const float* __restrict__ s,
                                                      const float* __restrict__ bb,
                                                      const int* __restrict__ mask,
                                                      u16* __restrict__ y, int do_zero) {
  int row = blockIdx.x * 4 + (threadIdx.x >> 6);
  int lane = threadIdx.x & 63;
  int b = row >> 10, l = row & 1023;
  bool pad = do_zero && (mask[b * L_ + l] == 0);
  float4* xr = reinterpret_cast<float4*>(nodes + (size_t)row * H_);
  float4 v[4];
  float sum = 0.f, sq = 0.f;
#pragma unroll
  for (int j = 0; j < 4; ++j) {
    v[j] = pad ? float4{0.f, 0.f, 0.f, 0.f} : xr[lane + 64 * j];
    sum += v[j].x + v[j].y + v[j].z + v[j].w;
    sq += v[j].x * v[j].x + v[j].y * v[j].y + v[j].z * v[j].z + v[j].w * v[j].w;
  }
  if (pad) {
#pragma unroll
    for (int j = 0; j < 4; ++j) xr[lane + 64 * j] = float4{0.f, 0.f, 0.f, 0.f};
  }
#pragma unroll
  for (int off = 32; off; off >>= 1) {
    sum += __shfl_xor(sum, off);
    sq += __shfl_xor(sq, off);
  }
  float mu = sum * (1.f / (float)H_);
  float rstd = rsqrtf(sq * (1.f / (float)H_) - mu * mu + 1e-5f);
  ushort4* yr = reinterpret_cast<ushort4*>(y + (size_t)row * H_);
#pragma unroll
  for (int j = 0; j < 4; ++j) {
    int c4 = lane + 64 * j;
    float4 sc = reinterpret_cast<const float4*>(s)[c4];
    float4 bc = reinterpret_cast<const float4*>(bb)[c4];
    ushort4 o;
    o.x = f2bf((v[j].x - mu) * rstd * sc.x + bc.x);
    o.y = f2bf((v[j].y - mu) * rstd * sc.y + bc.y);
    o.z = f2bf((v[j].z - mu) * rstd * sc.z + bc.z);
    o.w = f2bf((v[j].w - mu) * rstd * sc.w + bc.w);
    yr[c4] = o;
  }
}

// ================= 128x128 MFMA GEMM, BK=64 (two 32-col halves) =================
// Single-buffer 2-barrier loop, 16 K-steps, 32 MFMA/step/wave.

#define GEMM_PROLOGUE(XPTR, WPTR)                                              \
  __shared__ __align__(16) u16 sX[2][128 * 32];                                \
  __shared__ __align__(16) u16 sW[2][128 * 32];                                \
  const int t = threadIdx.x;                                                   \
  const int w = t >> 6, lane = t & 63;                                         \
  const int wm = w >> 1, wn = w & 1;                                           \
  const int r4 = lane >> 2, slot = lane & 3;                                   \
  const int rowS0 = w * 16 + r4, rowS1 = 64 + rowS0;                           \
  const int colS0 = ((slot ^ ((rowS0 >> 1) & 3)) << 3);                        \
  const int colS1 = ((slot ^ ((rowS1 >> 1) & 3)) << 3);                        \
  const u16* gX0 = (XPTR) + (size_t)(bm + rowS0) * 1024 + colS0;               \
  const u16* gX1 = (XPTR) + (size_t)(bm + rowS1) * 1024 + colS1;               \
  const u16* gW0 = (WPTR) + (size_t)(bn + rowS0) * 1024 + colS0;               \
  const u16* gW1 = (WPTR) + (size_t)(bn + rowS1) * 1024 + colS1;               \
  u16* lX0a = sX[0] + w * 512;                                                 \
  u16* lX0b = sX[1] + w * 512;                                                 \
  u16* lX1a = sX[0] + (4 + w) * 512;                                           \
  u16* lX1b = sX[1] + (4 + w) * 512;                                           \
  u16* lW0a = sW[0] + w * 512;                                                 \
  u16* lW0b = sW[1] + w * 512;                                                 \
  u16* lW1a = sW[0] + (4 + w) * 512;                                           \
  u16* lW1b = sW[1] + (4 + w) * 512;                                           \
  const int kidx = (((lane >> 4) ^ ((lane >> 1) & 3)) << 3);                   \
  f32x4 acc[4][4];                                                             \
  _Pragma("unroll") for (int i_ = 0; i_ < 4; ++i_)                             \
      _Pragma("unroll") for (int j_ = 0; j_ < 4; ++j_)                         \
          acc[i_][j_] = f32x4{0.f, 0.f, 0.f, 0.f};

#define GEMM_KLOOP64(AROWBASE, BROWBASE, ASRC, BSRC)                           \
  for (int ck = 0; ck < 1024; ck += 64) {                                      \
    gl_lds16(gX0, lX0a);                                                       \
    gl_lds16(gX0 + 32, lX0b);                                                  \
    gl_lds16(gX1, lX1a);                                                       \
    gl_lds16(gX1 + 32, lX1b);                                                  \
    gl_lds16(gW0, lW0a);                                                       \
    gl_lds16(gW0 + 32, lW0b);                                                  \
    gl_lds16(gW1, lW1a);                                                       \
    gl_lds16(gW1 + 32, lW1b);                                                  \
    gX0 += 64; gX1 += 64; gW0 += 64; gW1 += 64;                                \
    __syncthreads();                                                           \
    _Pragma("unroll") for (int h = 0; h < 2; ++h) {                            \
      short8 af_[4], bf_[4];                                                   \
      _Pragma("unroll") for (int mf = 0; mf < 4; ++mf)                         \
          af_[mf] = *reinterpret_cast<const short8*>(                          \
              &ASRC[h][((AROWBASE) + mf * 16) * 32 + kidx]);                   \
      _Pragma("unroll") for (int nf = 0; nf < 4; ++nf)                         \
          bf_[nf] = *reinterpret_cast<const short8*>(                          \
              &BSRC[h][((BROWBASE) + nf * 16) * 32 + kidx]);                   \
      _Pragma("unroll") for (int mf = 0; mf < 4; ++mf)                         \
          _Pragma("unroll") for (int nf = 0; nf < 4; ++nf)                     \
              acc[mf][nf] = __builtin_amdgcn_mfma_f32_16x16x32_bf16(           \
                  af_[mf], bf_[nf], acc[mf][nf], 0, 0, 0);                     \
    }                                                                          \
    __syncthreads();                                                           \
  }

// ---- 5-in-1 GEMM, swapped orientation (A=W -> M=o, B=X -> N=l(B*L)) ----
__global__ __launch_bounds__(256, 3) void k_gemm5(const u16* __restrict__ wq,
                                                  const u16* __restrict__ wk,
                                                  const u16* __restrict__ wv,
                                                  const float* __restrict__ bq,
                                                  const float* __restrict__ bk,
                                                  const float* __restrict__ bv,
                                                  const u16* __restrict__ xn,
                                                  const u16* __restrict__ embs,
                                                  u16* __restrict__ Y) {
  const int bm = blockIdx.x * 128;            // bl rows
  const int which = blockIdx.y >> 3;
  const int bn = (blockIdx.y & 7) * 128;      // o
  const u16* W = (which == 0) ? wq : ((which == 1 || which == 3) ? wk : wv);
  const float* bias = (which == 0) ? bq : ((which == 1 || which == 3) ? bk : bv);
  const u16* X = (which < 3) ? xn : embs;
  u16* Yw = Y + (size_t)which * ((size_t)B_ * L_ * ND_);

  GEMM_PROLOGUE(X, W)
  const int rW = wm * 64 + (lane & 15);
  const int rX = wn * 64 + (lane & 15);
  GEMM_KLOOP64(rW, rX, sW, sX)

#pragma unroll
  for (int mo = 0; mo < 4; ++mo) {
    int o0 = bn + wm * 64 + mo * 16 + ((lane >> 4) << 2);
    float4 bs = *reinterpret_cast<const float4*>(bias + o0);
#pragma unroll
    for (int nl = 0; nl < 4; ++nl) {
      int bl = bm + wn * 64 + nl * 16 + (lane & 15);
      f32x4 vv = acc[mo][nl];
      ushort4 ov;
      ov.x = f2bf(vv[0] + bs.x);
      ov.y = f2bf(vv[1] + bs.y);
      ov.z = f2bf(vv[2] + bs.z);
      ov.w = f2bf(vv[3] + bs.w);
      *reinterpret_cast<ushort4*>(&Yw[(size_t)bl * 1024 + o0]) = ov;
    }
  }
}

// ---- Wo GEMM; nodes[B*L,H] += leaky(val); nodes_bf = bf16 ----
__global__ __launch_bounds__(256, 3) void k_gemm_wo(const u16* __restrict__ W,
                                                    const float* __restrict__ bias,
                                                    const u16* __restrict__ X,
                                                    float* __restrict__ nodes,
                                                    u16* __restrict__ nodes_bf) {
  const int bm = blockIdx.x * 128;  // bl
  const int bn = blockIdx.y * 128;  // o
  GEMM_PROLOGUE(X, W)
  const int rW = wm * 64 + (lane & 15);
  const int rX = wn * 64 + (lane & 15);
  GEMM_KLOOP64(rW, rX, sW, sX)

#pragma unroll
  for (int mo = 0; mo < 4; ++mo) {
    int o0 = bn + wm * 64 + mo * 16 + ((lane >> 4) << 2);
    float4 bs = *reinterpret_cast<const float4*>(bias + o0);
#pragma unroll
    for (int nl = 0; nl < 4; ++nl) {
      int bl = bm + wn * 64 + nl * 16 + (lane & 15);
      size_t ni = (size_t)bl * 1024 + o0;
      float4 curv = *reinterpret_cast<const float4*>(&nodes[ni]);
      f32x4 vv = acc[mo][nl];
      float r0 = vv[0] + bs.x; r0 = curv.x + (r0 > 0.f ? r0 : 0.01f * r0);
      float r1 = vv[1] + bs.y; r1 = curv.y + (r1 > 0.f ? r1 : 0.01f * r1);
      float r2 = vv[2] + bs.z; r2 = curv.z + (r2 > 0.f ? r2 : 0.01f * r2);
      float r3 = vv[3] + bs.w; r3 = curv.w + (r3 > 0.f ? r3 : 0.01f * r3);
      *reinterpret_cast<float4*>(&nodes[ni]) = float4{r0, r1, r2, r3};
      ushort4 ov;
      ov.x = f2bf(r0); ov.y = f2bf(r1); ov.z = f2bf(r2); ov.w = f2bf(r3);
      *reinterpret_cast<ushort4*>(&nodes_bf[ni]) = ov;
    }
  }
}

// ---------- dual matvec (rk, rv) ----------
__global__ __launch_bounds__(256) void k_matvec2(const float* __restrict__ W0,
                                                 const float* __restrict__ b0,
                                                 float* __restrict__ y0,
                                                 const float* __restrict__ W1,
                                                 const float* __restrict__ b1,
                                                 float* __restrict__ y1,
                                                 const float* __restrict__ x) {
  int b = blockIdx.y;
  int z = blockIdx.z;
  const float* W = z ? W1 : W0;
  const float* bias = z ? b1 : b0;
  float* y = z ? y1 : y0;
  int o = blockIdx.x * 4 + (threadIdx.x >> 6);
  int lane = threadIdx.x & 63;
  const float* wr = W + (size_t)o * 1024;
  const float* xb = x + (size_t)b * 1024;
  float acc = 0.f;
  for (int c = lane; c < 1024; c += 64) acc += wr[c] * xb[c];
#pragma unroll
  for (int off = 32; off; off >>= 1) acc += __shfl_xor(acc, off);
  if (lane == 0) y[(size_t)b * 1024 + o] = acc + bias[o];
}

// ---------- single matvec ----------
__global__ __launch_bounds__(256) void k_matvec(const float* __restrict__ W,
                                                const float* __restrict__ bias,
                                                const float* __restrict__ x,
                                                float* __restrict__ y, int leaky) {
  int b = blockIdx.y;
  int o = blockIdx.x * 4 + (threadIdx.x >> 6);
  int lane = threadIdx.x & 63;
  const float* wr = W + (size_t)o * 1024;
  const float* xb = x + (size_t)b * 1024;
  float acc = 0.f;
  for (int c = lane; c < 1024; c += 64) acc += wr[c] * xb[c];
#pragma unroll
  for (int off = 32; off; off >>= 1) acc += __shfl_xor(acc, off);
  if (lane == 0) {
    acc += bias[o];
    if (leaky) acc = acc > 0.f ? acc : 0.01f * acc;
    y[(size_t)b * 1024 + o] = acc;
  }
}

// ---------- msa1 ring attention: 16 d per thread, 4 l per block ----------
__global__ __launch_bounds__(256) void k_msa1(const u16* __restrict__ q,
                                              const u16* __restrict__ k,
                                              const u16* __restrict__ v,
                                              const u16* __restrict__ ke,
                                              const u16* __restrict__ ve,
                                              const float* __restrict__ rk,
                                              const float* __restrict__ rv,
                                              u16* __restrict__ attbf) {
  int t = threadIdx.x;
  int wv = t >> 6, lane = t & 63;
  int head = lane >> 2, dq = lane & 3;
  int l = blockIdx.x * 4 + wv;
  int b = blockIdx.z;
  size_t row = ((size_t)(b * 1024 + l)) * 1024 + head * 64 + dq * 16;
  size_t rbase = (size_t)b * 1024 + head * 64 + dq * 16;

  float qf[16];
  {
    const short8* qp = reinterpret_cast<const short8*>(q + row);
#pragma unroll
    for (int j = 0; j < 2; ++j) {
      short8 qv = qp[j];
#pragma unroll
      for (int e = 0; e < 8; ++e) qf[j * 8 + e] = bf2f((u16)qv[e]);
    }
  }
  float s[7];
#pragma unroll
  for (int u = 0; u < 5; ++u) {
    int lk = l + u - 2;
    float su = 0.f;
    if (lk >= 0 && lk < L_) {
      const short8* kp = reinterpret_cast<const short8*>(
          k + ((size_t)(b * 1024 + lk)) * 1024 + head * 64 + dq * 16);
#pragma unroll
      for (int j = 0; j < 2; ++j) {
        short8 kv = kp[j];
#pragma unroll
        for (int e = 0; e < 8; ++e) su = fmaf(qf[j * 8 + e], bf2f((u16)kv[e]), su);
      }
    }
    s[u] = su;
  }
  {
    float su = 0.f;
    const short8* kp = reinterpret_cast<const short8*>(ke + row);
#pragma unroll
    for (int j = 0; j < 2; ++j) {
      short8 kv = kp[j];
#pragma unroll
      for (int e = 0; e < 8; ++e) su = fmaf(qf[j * 8 + e], bf2f((u16)kv[e]), su);
    }
    s[5] = su;
  }
  {
    float su = 0.f;
    const float4* rp = reinterpret_cast<const float4*>(rk + rbase);
#pragma unroll
    for (int j = 0; j < 4; ++j) {
      float4 r4 = rp[j];
      su = fmaf(qf[j * 4 + 0], r4.x, su);
      su = fmaf(qf[j * 4 + 1], r4.y, su);
      su = fmaf(qf[j * 4 + 2], r4.z, su);
      su = fmaf(qf[j * 4 + 3], r4.w, su);
    }
    s[6] = su;
  }
  // combine 4 d-quarters (lane bits 0,1)
#pragma unroll
  for (int u = 0; u < 7; ++u) {
    s[u] += __shfl_xor(s[u], 1);
    s[u] += __shfl_xor(s[u], 2);
  }
  float m = -1e30f;
#pragma unroll
  for (int u = 0; u < 7; ++u) {
    s[u] *= 0.125f;
    m = fmaxf(m, s[u]);
  }
  float e[7], tot = 0.f;
#pragma unroll
  for (int u = 0; u < 7; ++u) {
    e[u] = expf(s[u] - m);
    tot += e[u];
  }
  float inv = 1.f / tot;
#pragma unroll
  for (int u = 0; u < 7; ++u) e[u] *= inv;

  float av[16];
  {
    const float4* rp = reinterpret_cast<const float4*>(rv + rbase);
#pragma unroll
    for (int j = 0; j < 4; ++j) {
      float4 r4 = rp[j];
      av[j * 4 + 0] = e[6] * r4.x;
      av[j * 4 + 1] = e[6] * r4.y;
      av[j * 4 + 2] = e[6] * r4.z;
      av[j * 4 + 3] = e[6] * r4.w;
    }
  }
  {
    const short8* vp = reinterpret_cast<const short8*>(ve + row);
#pragma unroll
    for (int j = 0; j < 2; ++j) {
      short8 vvv = vp[j];
#pragma unroll
      for (int ee = 0; ee < 8; ++ee) av[j * 8 + ee] = fmaf(e[5], bf2f((u16)vvv[ee]), av[j * 8 + ee]);
    }
  }
#pragma unroll
  for (int u = 0; u < 5; ++u) {
    int lk = l + u - 2;
    if (lk >= 0 && lk < L_) {
      const short8* vp = reinterpret_cast<const short8*>(
          v + ((size_t)(b * 1024 + lk)) * 1024 + head * 64 + dq * 16);
#pragma unroll
      for (int j = 0; j < 2; ++j) {
        short8 vvv = vp[j];
#pragma unroll
        for (int ee = 0; ee < 8; ++ee) av[j * 8 + ee] = fmaf(e[u], bf2f((u16)vvv[ee]), av[j * 8 + ee]);
      }
    }
  }
  u16 ob[16];
#pragma unroll
  for (int j = 0; j < 16; ++j) ob[j] = f2bf(av[j]);
  uint4* d4 = reinterpret_cast<uint4*>(attbf + row);
  const uint4* s4 = reinterpret_cast<const uint4*>(ob);
  d4[0] = s4[0];
  d4[1] = s4[1];
}

// ================= factorized msa2 (v = k, faithful) =================
// k_p = swk@x_p + bk  =>  softmax(q.k_p) == softmax((swk^T q).x_p)  (const shift),
// att = swk @ (sum_p alpha_p x_p) + bk.

// qt[b][n][c] = sum_d swk[n*64+d][c] * rq[b][n*64+d]
__global__ __launch_bounds__(256) void k_qt(const float* __restrict__ swk,
                                            const float* __restrict__ rq,
                                            float* __restrict__ qt) {
  int c = blockIdx.x * 256 + threadIdx.x;
  int n = blockIdx.y, b = blockIdx.z;
  __shared__ float rqs[64];
  if (threadIdx.x < 64) rqs[threadIdx.x] = rq[(size_t)b * 1024 + n * 64 + threadIdx.x];
  __syncthreads();
  const float* wr = swk + (size_t)(n * 64) * 1024 + c;
  float acc = 0.f;
#pragma unroll 8
  for (int d = 0; d < 64; ++d) acc = fmaf(rqs[d], wr[(size_t)d * 1024], acc);
  qt[((size_t)b * 16 + n) * 1024 + c] = acc;
}

// se[b][n][p] = exp(qt.x_p / 8) (0 if masked); pE partial sums per wave.
// x_0 = relay (fp32), x_p = nodes_bf[p-1] (bf16). wave handles 16 consecutive p.
__global__ __launch_bounds__(256) void k_score(const float* __restrict__ qt,
                                               const u16* __restrict__ nodes_bf,
                                               const float* __restrict__ relay,
                                               const int* __restrict__ mask,
                                               float* __restrict__ se,
                                               float* __restrict__ pE) {
  int pblk = blockIdx.x, n = blockIdx.y, b = blockIdx.z;
  int wv = threadIdx.x >> 6, lane = threadIdx.x & 63;
  __shared__ float qts[1024];
  size_t bn = (size_t)b * 16 + n;
  for (int i = threadIdx.x; i < 1024; i += 256) qts[i] = qt[bn * 1024 + i];
  __syncthreads();
  float esum = 0.f;
  for (int j = 0; j < 16; ++j) {
    int p = pblk * 64 + wv * 16 + j;
    if (p > 1024) break;  // wave-uniform
    float sc = 0.f;
    if (p == 0) {
      const float* xr = relay + (size_t)b * 1024;
#pragma unroll 4
      for (int it = 0; it < 16; ++it) {
        int c = it * 64 + lane;
        sc = fmaf(qts[c], xr[c], sc);
      }
    } else {
      const u16* xr = nodes_bf + ((size_t)b * 1024 + (p - 1)) * 1024;
#pragma unroll 4
      for (int it = 0; it < 16; ++it) {
        int c = it * 64 + lane;
        sc = fmaf(qts[c], bf2f(xr[c]), sc);
      }
    }
#pragma unroll
    for (int off = 32; off; off >>= 1) sc += __shfl_xor(sc, off);
    float e;
    if (p > 0 && mask[b * L_ + p - 1] == 0) e = 0.f;
    else e = expf(sc * 0.125f);
    if (lane == 0) se[bn * 1025 + p] = e;
    esum += e;
  }
  if (lane == 0) pE[bn * 68 + pblk * 4 + wv] = esum;
}

// y[b][n][c] = (sum_p se[p] * x_p[c]) / E
__global__ __launch_bounds__(256) void k_ysum(const float* __restrict__ se,
                                              const float* __restrict__ pE,
                                              const u16* __restrict__ nodes_bf,
                                              const float* __restrict__ relay,
                                              float* __restrict__ y) {
  int cblk = blockIdx.x, n = blockIdx.y, b = blockIdx.z;
  int c = cblk * 256 + threadIdx.x;
  __shared__ float ses[1025];
  size_t bn = (size_t)b * 16 + n;
  for (int i = threadIdx.x; i < 1025; i += 256) ses[i] = se[bn * 1025 + i];
  __syncthreads();
  float E = 0.f;
  for (int j = 0; j < 68; ++j) E += pE[bn * 68 + j];
  float acc = ses[0] * relay[(size_t)b * 1024 + c];
  const u16* xc = nodes_bf + (size_t)b * 1024 * 1024 + c;
  for (int p = 1; p <= 1024; ++p)
    acc = fmaf(ses[p], bf2f(xc[(size_t)(p - 1) * 1024]), acc);
  y[bn * 1024 + c] = acc / E;
}

// satt[b][o] = swk[o,:] . y[b][o>>6,:] + bk[o]
__global__ __launch_bounds__(256) void k_att(const float* __restrict__ swk,
                                             const float* __restrict__ bk,
                                             const float* __restrict__ y,
                                             float* __restrict__ satt) {
  int b = blockIdx.y;
  int o = blockIdx.x * 4 + (threadIdx.x >> 6);
  int lane = threadIdx.x & 63;
  int n = o >> 6;
  const float* wr = swk + (size_t)o * 1024;
  const float* yr = y + ((size_t)b * 16 + n) * 1024;
  float acc = 0.f;
  for (int c = lane; c < 1024; c += 64) acc = fmaf(wr[c], yr[c], acc);
#pragma unroll
  for (int off = 32; off; off >>= 1) acc += __shfl_xor(acc, off);
  if (lane == 0) satt[(size_t)b * 1024 + o] = acc + bk[o];
}

// ---------- final: out = pad ? 0 : nodes ----------
__global__ void k_final(const float* __restrict__ nodes, const int* __restrict__ mask,
                        float* __restrict__ out) {
  int i = blockIdx.x * 256 + threadIdx.x;
  int row = i >> 8;
  int b = row >> 10, l = row & 1023;
  float4 v = (mask[b * L_ + l] == 0) ? float4{0.f, 0.f, 0.f, 0.f}
                                     : reinterpret_cast<const float4*>(nodes)[i];
  reinterpret_cast<float4*>(out)[i] = v;
}

__global__ void k_copy_relay(const float* __restrict__ relay, float* __restrict__ out) {
  int i = blockIdx.x * 256 + threadIdx.x;
  out[i] = relay[i];
}

}  // namespace

extern "C" void kernel_launch(void* const* d_in, const int* in_sizes, int n_in,
                              void* d_out, int out_size, void* d_ws, size_t ws_size,
                              hipStream_t stream) {
  (void)in_sizes; (void)n_in; (void)out_size; (void)ws_size;
  const float* data = (const float*)d_in[0];
  const int* mask = (const int*)d_in[1];
  const float* ln_s = (const float*)d_in[2];
  const float* ln_b = (const float*)d_in[3];
  const float* rwq = (const float*)d_in[4];
  const float* rwq_b = (const float*)d_in[5];
  const float* rwk = (const float*)d_in[6];
  const float* rwk_b = (const float*)d_in[7];
  const float* rwv = (const float*)d_in[8];
  const float* rwv_b = (const float*)d_in[9];
  const float* rwo = (const float*)d_in[10];
  const float* rwo_b = (const float*)d_in[11];
  const float* swq = (const float*)d_in[12];
  const float* swq_b = (const float*)d_in[13];
  const float* swk = (const float*)d_in[14];
  const float* swk_b = (const float*)d_in[15];
  const float* swo = (const float*)d_in[16];
  const float* swo_b = (const float*)d_in[17];
  float* out = (float*)d_out;

  const size_t SZ = (size_t)B_ * ND_ * L_;  // 4M elements
  float* f = (float*)d_ws;
  float* nodes = f; f += SZ;                 // fp32 [B,L,H]
  float* part = f; f += (size_t)B_ * 8 * H_;
  float* relay = f; f += B_ * H_;
  float* rk = f; f += B_ * ND_;
  float* rv = f; f += B_ * ND_;
  float* rq = f; f += B_ * ND_;
  float* satt = f; f += B_ * ND_;
  float* qt = f; f += (size_t)B_ * 16 * 1024;
  float* sebuf = f; f += (size_t)B_ * 16 * 1025;
  float* pE = f; f += (size_t)B_ * 16 * 68;
  float* ybuf = f; f += (size_t)B_ * 16 * 1024;
  u16* u = (u16*)f;
  u16* xn_bf = u; u += SZ;       // [B,L,H]
  u16* embs_bf = u; u += SZ;     // [B,L,H]
  u16* att_bf = u; u += SZ;      // [B,L,ND]
  u16* nodes_bf = u; u += SZ;    // [B,L,H]
  u16* qkv5_bf = u; u += 5 * SZ; // [5][B,L,ND]: q,k,v,ke,ve
  u16* wq_bf = u; u += SZ;
  u16* wk_bf = u; u += SZ;
  u16* wv_bf = u; u += SZ;
  u16* wo_bf = u; u += SZ;

  k_prep<<<dim3(4096, 6), 256, 0, stream>>>(data, rwq, rwk, rwv, rwo,
                                            embs_bf, wq_bf, wk_bf, wv_bf, wo_bf, nodes);
  k_relay_part<<<dim3(H_ / 256, 8, B_), 256, 0, stream>>>(data, part);
  k_relay_reduce<<<dim3((B_ * H_) / 256), 256, 0, stream>>>(part, relay);

  for (int i = 0; i < ITERS_; ++i) {
    const u16* wq_i = wq_bf + (size_t)i * ND_ * H_;
    const u16* wk_i = wk_bf + (size_t)i * ND_ * H_;
    const u16* wv_i = wv_bf + (size_t)i * ND_ * H_;
    const u16* wo_i = wo_bf + (size_t)i * H_ * ND_;
    const float* swk_i = swk + (size_t)i * ND_ * H_;

    k_layernorm_bf<<<dim3(B_ * L_ / 4), 256, 0, stream>>>(nodes, ln_s + i * H_, ln_b + i * H_,
                                                          mask, xn_bf, i > 0 ? 1 : 0);
    k_gemm5<<<dim3(32, 40), 256, 0, stream>>>(wq_i, wk_i, wv_i,
                                              rwq_b + i * ND_, rwk_b + i * ND_, rwv_b + i * ND_,
                                              xn_bf, embs_bf, qkv5_bf);
    k_matvec2<<<dim3(256, B_, 2), 256, 0, stream>>>(
        rwk + (size_t)i * ND_ * H_, rwk_b + i * ND_, rk,
        rwv + (size_t)i * ND_ * H_, rwv_b + i * ND_, rv, relay);
    k_msa1<<<dim3(L_ / 4, 1, B_), 256, 0, stream>>>(qkv5_bf, qkv5_bf + SZ, qkv5_bf + 2 * SZ,
                                                    qkv5_bf + 3 * SZ, qkv5_bf + 4 * SZ, rk, rv, att_bf);
    // rq = swq @ relay + bq (old relay); qt = per-head swk^T rq
    k_matvec<<<dim3(256, B_), 256, 0, stream>>>(swq + (size_t)i * ND_ * H_, swq_b + i * ND_,
                                                relay, rq, 0);
    k_qt<<<dim3(4, NH_, B_), 256, 0, stream>>>(swk_i, rq, qt);
    // nodes += leaky(Wo @ att + bo); nodes_bf = bf16(nodes)
    k_gemm_wo<<<dim3(32, 8), 256, 0, stream>>>(wo_i, rwo_b + i * H_, att_bf, nodes, nodes_bf);
    // factorized star attention
    k_score<<<dim3(17, NH_, B_), 256, 0, stream>>>(qt, nodes_bf, relay, mask, sebuf, pE);
    k_ysum<<<dim3(4, NH_, B_), 256, 0, stream>>>(sebuf, pE, nodes_bf, relay, ybuf);
    k_att<<<dim3(256, B_), 256, 0, stream>>>(swk_i, swk_b + i * ND_, ybuf, satt);
    k_matvec<<<dim3(256, B_), 256, 0, stream>>>(swo + (size_t)i * H_ * ND_, swo_b + i * H_,
                                                satt, relay, 1);
  }
  k_final<<<4096, 256, 0, stream>>>(nodes, mask, out);
  k_copy_relay<<<dim3((B_ * H_) / 256), 256, 0, stream>>>(relay, out + (size_t)B_ * L_ * H_);
}

// Round 9
// 711.731 us; speedup vs baseline: 1.2459x; 1.2459x over previous
//
#include <hip/hip_runtime.h>
#include <math.h>

namespace {

constexpr int B_ = 4, L_ = 1024, H_ = 1024, NH_ = 16, HD_ = 64, ND_ = 1024, ITERS_ = 4;

typedef unsigned short u16;
typedef __attribute__((ext_vector_type(8))) short short8;
typedef __attribute__((ext_vector_type(4))) float f32x4;

__device__ inline u16 f2bf(float f) {
  unsigned u = __builtin_bit_cast(unsigned, f);
  u += 0x7FFFu + ((u >> 16) & 1u);
  return (u16)(u >> 16);
}
__device__ inline float bf2f(u16 v) {
  unsigned u = ((unsigned)v) << 16;
  return __builtin_bit_cast(float, u);
}

__device__ inline void gl_lds16(const u16* g, u16* l) {
  __builtin_amdgcn_global_load_lds((const __attribute__((address_space(1))) void*)g,
                                   (__attribute__((address_space(3))) void*)l, 16, 0, 0);
}

// ---------- prep: 6 f2bf conversions + nodes copy, one dispatch ----------
__global__ void k_prep(const float* __restrict__ data, const float* __restrict__ rwq,
                       const float* __restrict__ rwk, const float* __restrict__ rwv,
                       const float* __restrict__ rwo, const float* __restrict__ swk,
                       u16* __restrict__ embs_bf, u16* __restrict__ wq_bf,
                       u16* __restrict__ wk_bf, u16* __restrict__ wv_bf,
                       u16* __restrict__ wo_bf, u16* __restrict__ swk_bf,
                       float* __restrict__ nodes) {
  int i = blockIdx.x * 256 + threadIdx.x;
  int which = blockIdx.y;
  if (which == 6) {
    reinterpret_cast<float4*>(nodes)[i] = reinterpret_cast<const float4*>(data)[i];
    return;
  }
  const float* src;
  u16* dst;
  switch (which) {
    case 0: src = data; dst = embs_bf; break;
    case 1: src = rwq; dst = wq_bf; break;
    case 2: src = rwk; dst = wk_bf; break;
    case 3: src = rwv; dst = wv_bf; break;
    case 4: src = rwo; dst = wo_bf; break;
    default: src = swk; dst = swk_bf; break;
  }
  float4 v = reinterpret_cast<const float4*>(src)[i];
  ushort4 o;
  o.x = f2bf(v.x); o.y = f2bf(v.y); o.z = f2bf(v.z); o.w = f2bf(v.w);
  reinterpret_cast<ushort4*>(dst)[i] = o;
}

// ---------- relay init ----------
__global__ void k_relay_part(const float* __restrict__ data, float* __restrict__ part) {
  int b = blockIdx.z, chunk = blockIdx.y;
  int c = blockIdx.x * 256 + threadIdx.x;
  const float* p = data + ((size_t)b * L_ + chunk * 128) * H_ + c;
  float acc = 0.f;
  for (int l = 0; l < 128; ++l) acc += p[(size_t)l * H_];
  part[((size_t)b * 8 + chunk) * H_ + c] = acc;
}
__global__ void k_relay_reduce(const float* __restrict__ part, float* __restrict__ relay) {
  int i = blockIdx.x * 256 + threadIdx.x;
  int b = i >> 10, c = i & 1023;
  float acc = 0.f;
  for (int j = 0; j < 8; ++j) acc += part[((size_t)b * 8 + j) * H_ + c];
  relay[i] = acc * (1.f / (float)L_);
}

// ---------- LayerNorm rows of nodes [B,L,H]; fused pad-row zeroing ----------
__global__ __launch_bounds__(256) void k_layernorm_bf(float* __restrict__ nodes,
                                                      const float* __restrict__ s,
                                                      const float* __restrict__ bb,
                                                      const int* __restrict__ mask,
                                                      u16* __restrict__ y, int do_zero) {
  int row = blockIdx.x * 4 + (threadIdx.x >> 6);
  int lane = threadIdx.x & 63;
  int b = row >> 10, l = row & 1023;
  bool pad = do_zero && (mask[b * L_ + l] == 0);
  float4* xr = reinterpret_cast<float4*>(nodes + (size_t)row * H_);
  float4 v[4];
  float sum = 0.f, sq = 0.f;
#pragma unroll
  for (int j = 0; j < 4; ++j) {
    v[j] = pad ? float4{0.f, 0.f, 0.f, 0.f} : xr[lane + 64 * j];
    sum += v[j].x + v[j].y + v[j].z + v[j].w;
    sq += v[j].x * v[j].x + v[j].y * v[j].y + v[j].z * v[j].z + v[j].w * v[j].w;
  }
  if (pad) {
#pragma unroll
    for (int j = 0; j < 4; ++j) xr[lane + 64 * j] = float4{0.f, 0.f, 0.f, 0.f};
  }
#pragma unroll
  for (int off = 32; off; off >>= 1) {
    sum += __shfl_xor(sum, off);
    sq += __shfl_xor(sq, off);
  }
  float mu = sum * (1.f / (float)H_);
  float rstd = rsqrtf(sq * (1.f / (float)H_) - mu * mu + 1e-5f);
  ushort4* yr = reinterpret_cast<ushort4*>(y + (size_t)row * H_);
#pragma unroll
  for (int j = 0; j < 4; ++j) {
    int c4 = lane + 64 * j;
    float4 sc = reinterpret_cast<const float4*>(s)[c4];
    float4 bc = reinterpret_cast<const float4*>(bb)[c4];
    ushort4 o;
    o.x = f2bf((v[j].x - mu) * rstd * sc.x + bc.x);
    o.y = f2bf((v[j].y - mu) * rstd * sc.y + bc.y);
    o.z = f2bf((v[j].z - mu) * rstd * sc.z + bc.z);
    o.w = f2bf((v[j].w - mu) * rstd * sc.w + bc.w);
    yr[c4] = o;
  }
}

// ================= 128x128 MFMA GEMM, BK=64, XCD-swizzled =================

#define GEMM_PROLOGUE(XPTR, WPTR)                                              \
  __shared__ __align__(16) u16 sX[2][128 * 32];                                \
  __shared__ __align__(16) u16 sW[2][128 * 32];                                \
  const int t = threadIdx.x;                                                   \
  const int w = t >> 6, lane = t & 63;                                         \
  const int wm = w >> 1, wn = w & 1;                                           \
  const int r4 = lane >> 2, slot = lane & 3;                                   \
  const int rowS0 = w * 16 + r4, rowS1 = 64 + rowS0;                           \
  const int colS0 = ((slot ^ ((rowS0 >> 1) & 3)) << 3);                        \
  const int colS1 = ((slot ^ ((rowS1 >> 1) & 3)) << 3);                        \
  const u16* gX0 = (XPTR) + (size_t)(bm + rowS0) * 1024 + colS0;               \
  const u16* gX1 = (XPTR) + (size_t)(bm + rowS1) * 1024 + colS1;               \
  const u16* gW0 = (WPTR) + (size_t)(bn + rowS0) * 1024 + colS0;               \
  const u16* gW1 = (WPTR) + (size_t)(bn + rowS1) * 1024 + colS1;               \
  u16* lX0a = sX[0] + w * 512;                                                 \
  u16* lX0b = sX[1] + w * 512;                                                 \
  u16* lX1a = sX[0] + (4 + w) * 512;                                           \
  u16* lX1b = sX[1] + (4 + w) * 512;                                           \
  u16* lW0a = sW[0] + w * 512;                                                 \
  u16* lW0b = sW[1] + w * 512;                                                 \
  u16* lW1a = sW[0] + (4 + w) * 512;                                           \
  u16* lW1b = sW[1] + (4 + w) * 512;                                           \
  const int kidx = (((lane >> 4) ^ ((lane >> 1) & 3)) << 3);                   \
  f32x4 acc[4][4];                                                             \
  _Pragma("unroll") for (int i_ = 0; i_ < 4; ++i_)                             \
      _Pragma("unroll") for (int j_ = 0; j_ < 4; ++j_)                         \
          acc[i_][j_] = f32x4{0.f, 0.f, 0.f, 0.f};

#define GEMM_KLOOP64(AROWBASE, BROWBASE, ASRC, BSRC)                           \
  for (int ck = 0; ck < 1024; ck += 64) {                                      \
    gl_lds16(gX0, lX0a);                                                       \
    gl_lds16(gX0 + 32, lX0b);                                                  \
    gl_lds16(gX1, lX1a);                                                       \
    gl_lds16(gX1 + 32, lX1b);                                                  \
    gl_lds16(gW0, lW0a);                                                       \
    gl_lds16(gW0 + 32, lW0b);                                                  \
    gl_lds16(gW1, lW1a);                                                       \
    gl_lds16(gW1 + 32, lW1b);                                                  \
    gX0 += 64; gX1 += 64; gW0 += 64; gW1 += 64;                                \
    __syncthreads();                                                           \
    _Pragma("unroll") for (int h = 0; h < 2; ++h) {                            \
      short8 af_[4], bf_[4];                                                   \
      _Pragma("unroll") for (int mf = 0; mf < 4; ++mf)                         \
          af_[mf] = *reinterpret_cast<const short8*>(                          \
              &ASRC[h][((AROWBASE) + mf * 16) * 32 + kidx]);                   \
      _Pragma("unroll") for (int nf = 0; nf < 4; ++nf)                         \
          bf_[nf] = *reinterpret_cast<const short8*>(                          \
              &BSRC[h][((BROWBASE) + nf * 16) * 32 + kidx]);                   \
      _Pragma("unroll") for (int mf = 0; mf < 4; ++mf)                         \
          _Pragma("unroll") for (int nf = 0; nf < 4; ++nf)                     \
              acc[mf][nf] = __builtin_amdgcn_mfma_f32_16x16x32_bf16(           \
                  af_[mf], bf_[nf], acc[mf][nf], 0, 0, 0);                     \
    }                                                                          \
    __syncthreads();                                                          \
  }

// ---- 5-in-1 GEMM, swapped orientation (A=W -> M=o, B=X -> N=l(B*L)) ----
// grid (32, 40); bijective XCD swizzle over nwg=1280 (1280%8==0).
__global__ __launch_bounds__(256, 3) void k_gemm5(const u16* __restrict__ wq,
                                                  const u16* __restrict__ wk,
                                                  const u16* __restrict__ wv,
                                                  const float* __restrict__ bq,
                                                  const float* __restrict__ bk,
                                                  const float* __restrict__ bv,
                                                  const u16* __restrict__ xn,
                                                  const u16* __restrict__ embs,
                                                  u16* __restrict__ Y) {
  const int orig = blockIdx.y * 32 + blockIdx.x;
  const int swz = (orig & 7) * 160 + (orig >> 3);
  const int sbx = swz & 31, sby = swz >> 5;
  const int bm = sbx * 128;            // bl rows
  const int which = sby >> 3;
  const int bn = (sby & 7) * 128;      // o
  const u16* W = (which == 0) ? wq : ((which == 1 || which == 3) ? wk : wv);
  const float* bias = (which == 0) ? bq : ((which == 1 || which == 3) ? bk : bv);
  const u16* X = (which < 3) ? xn : embs;
  u16* Yw = Y + (size_t)which * ((size_t)B_ * L_ * ND_);

  GEMM_PROLOGUE(X, W)
  const int rW = wm * 64 + (lane & 15);
  const int rX = wn * 64 + (lane & 15);
  GEMM_KLOOP64(rW, rX, sW, sX)

#pragma unroll
  for (int mo = 0; mo < 4; ++mo) {
    int o0 = bn + wm * 64 + mo * 16 + ((lane >> 4) << 2);
    float4 bs = *reinterpret_cast<const float4*>(bias + o0);
#pragma unroll
    for (int nl = 0; nl < 4; ++nl) {
      int bl = bm + wn * 64 + nl * 16 + (lane & 15);
      f32x4 vv = acc[mo][nl];
      ushort4 ov;
      ov.x = f2bf(vv[0] + bs.x);
      ov.y = f2bf(vv[1] + bs.y);
      ov.z = f2bf(vv[2] + bs.z);
      ov.w = f2bf(vv[3] + bs.w);
      *reinterpret_cast<ushort4*>(&Yw[(size_t)bl * 1024 + o0]) = ov;
    }
  }
}

// ---- Wo GEMM; nodes[B*L,H] += leaky(val); nodes_bf = bf16; grid (32,8) swizzled ----
__global__ __launch_bounds__(256, 3) void k_gemm_wo(const u16* __restrict__ W,
                                                    const float* __restrict__ bias,
                                                    const u16* __restrict__ X,
                                                    float* __restrict__ nodes,
                                                    u16* __restrict__ nodes_bf) {
  const int orig = blockIdx.y * 32 + blockIdx.x;
  const int swz = (orig & 7) * 32 + (orig >> 3);
  const int bm = (swz & 31) * 128;  // bl
  const int bn = (swz >> 5) * 128;  // o
  GEMM_PROLOGUE(X, W)
  const int rW = wm * 64 + (lane & 15);
  const int rX = wn * 64 + (lane & 15);
  GEMM_KLOOP64(rW, rX, sW, sX)

#pragma unroll
  for (int mo = 0; mo < 4; ++mo) {
    int o0 = bn + wm * 64 + mo * 16 + ((lane >> 4) << 2);
    float4 bs = *reinterpret_cast<const float4*>(bias + o0);
#pragma unroll
    for (int nl = 0; nl < 4; ++nl) {
      int bl = bm + wn * 64 + nl * 16 + (lane & 15);
      size_t ni = (size_t)bl * 1024 + o0;
      float4 curv = *reinterpret_cast<const float4*>(&nodes[ni]);
      f32x4 vv = acc[mo][nl];
      float r0 = vv[0] + bs.x; r0 = curv.x + (r0 > 0.f ? r0 : 0.01f * r0);
      float r1 = vv[1] + bs.y; r1 = curv.y + (r1 > 0.f ? r1 : 0.01f * r1);
      float r2 = vv[2] + bs.z; r2 = curv.z + (r2 > 0.f ? r2 : 0.01f * r2);
      float r3 = vv[3] + bs.w; r3 = curv.w + (r3 > 0.f ? r3 : 0.01f * r3);
      *reinterpret_cast<float4*>(&nodes[ni]) = float4{r0, r1, r2, r3};
      ushort4 ov;
      ov.x = f2bf(r0); ov.y = f2bf(r1); ov.z = f2bf(r2); ov.w = f2bf(r3);
      *reinterpret_cast<ushort4*>(&nodes_bf[ni]) = ov;
    }
  }
}

// ---- kkb GEMM, original orientation (A=X -> M=l, B=W -> N=o); out fp32 [b][o][1+l] ----
__global__ __launch_bounds__(256, 3) void k_gemm_kkb(const u16* __restrict__ W,
                                                     const float* __restrict__ bias,
                                                     const u16* __restrict__ X,
                                                     float* __restrict__ Y) {
  const int orig = blockIdx.y * 32 + blockIdx.x;
  const int swz = (orig & 7) * 32 + (orig >> 3);
  const int bm = (swz & 31) * 128;  // bl
  const int bn = (swz >> 5) * 128;  // o
  GEMM_PROLOGUE(X, W)
  const int rX = wm * 64 + (lane & 15);
  const int rW = wn * 64 + (lane & 15);
  GEMM_KLOOP64(rX, rW, sX, sW)

#pragma unroll
  for (int nf = 0; nf < 4; ++nf) {
    int o = bn + wn * 64 + nf * 16 + (lane & 15);
    float bs = bias[o];
#pragma unroll
    for (int mf = 0; mf < 4; ++mf) {
      int gl = bm + wm * 64 + mf * 16 + ((lane >> 4) << 2);
      int b = gl >> 10, l = gl & 1023;
      size_t yi = ((size_t)(b * 1024 + o)) * (size_t)(L_ + 1) + 1 + l;
      f32x4 v = acc[mf][nf];
#pragma unroll
      for (int r = 0; r < 4; ++r) Y[yi + r] = v[r] + bs;
    }
  }
}

// ---------- dual matvec with strides ----------
__global__ __launch_bounds__(256) void k_matvec2(const float* __restrict__ W0,
                                                 const float* __restrict__ b0,
                                                 float* __restrict__ y0, long sB0, long sO0,
                                                 const float* __restrict__ W1,
                                                 const float* __restrict__ b1,
                                                 float* __restrict__ y1, long sB1, long sO1,
                                                 const float* __restrict__ x) {
  int b = blockIdx.y;
  int z = blockIdx.z;
  const float* W = z ? W1 : W0;
  const float* bias = z ? b1 : b0;
  float* y = z ? y1 : y0;
  long sB = z ? sB1 : sB0, sO = z ? sO1 : sO0;
  int o = blockIdx.x * 4 + (threadIdx.x >> 6);
  int lane = threadIdx.x & 63;
  const float* wr = W + (size_t)o * 1024;
  const float* xb = x + (size_t)b * 1024;
  float acc = 0.f;
  for (int c = lane; c < 1024; c += 64) acc += wr[c] * xb[c];
#pragma unroll
  for (int off = 32; off; off >>= 1) acc += __shfl_xor(acc, off);
  if (lane == 0) y[(size_t)b * sB + (size_t)o * sO] = acc + bias[o];
}

// ---------- single matvec ----------
__global__ __launch_bounds__(256) void k_matvec(const float* __restrict__ W,
                                                const float* __restrict__ bias,
                                                const float* __restrict__ x,
                                                float* __restrict__ y, int leaky) {
  int b = blockIdx.y;
  int o = blockIdx.x * 4 + (threadIdx.x >> 6);
  int lane = threadIdx.x & 63;
  const float* wr = W + (size_t)o * 1024;
  const float* xb = x + (size_t)b * 1024;
  float acc = 0.f;
  for (int c = lane; c < 1024; c += 64) acc += wr[c] * xb[c];
#pragma unroll
  for (int off = 32; off; off >>= 1) acc += __shfl_xor(acc, off);
  if (lane == 0) {
    acc += bias[o];
    if (leaky) acc = acc > 0.f ? acc : 0.01f * acc;
    y[(size_t)b * 1024 + o] = acc;
  }
}

// ---------- msa1 ring attention: 16 d per thread, 4 l per block ----------
__global__ __launch_bounds__(256) void k_msa1(const u16* __restrict__ q,
                                              const u16* __restrict__ k,
                                              const u16* __restrict__ v,
                                              const u16* __restrict__ ke,
                                              const u16* __restrict__ ve,
                                              const float* __restrict__ rk,
                                              const float* __restrict__ rv,
                                              u16* __restrict__ attbf) {
  int t = threadIdx.x;
  int wv = t >> 6, lane = t & 63;
  int head = lane >> 2, dq = lane & 3;
  int l = blockIdx.x * 4 + wv;
  int b = blockIdx.z;
  size_t row = ((size_t)(b * 1024 + l)) * 1024 + head * 64 + dq * 16;
  size_t rbase = (size_t)b * 1024 + head * 64 + dq * 16;

  float qf[16];
  {
    const short8* qp = reinterpret_cast<const short8*>(q + row);
#pragma unroll
    for (int j = 0; j < 2; ++j) {
      short8 qv = qp[j];
#pragma unroll
      for (int e = 0; e < 8; ++e) qf[j * 8 + e] = bf2f((u16)qv[e]);
    }
  }
  float s[7];
#pragma unroll
  for (int u = 0; u < 5; ++u) {
    int lk = l + u - 2;
    float su = 0.f;
    if (lk >= 0 && lk < L_) {
      const short8* kp = reinterpret_cast<const short8*>(
          k + ((size_t)(b * 1024 + lk)) * 1024 + head * 64 + dq * 16);
#pragma unroll
      for (int j = 0; j < 2; ++j) {
        short8 kv = kp[j];
#pragma unroll
        for (int e = 0; e < 8; ++e) su = fmaf(qf[j * 8 + e], bf2f((u16)kv[e]), su);
      }
    }
    s[u] = su;
  }
  {
    float su = 0.f;
    const short8* kp = reinterpret_cast<const short8*>(ke + row);
#pragma unroll
    for (int j = 0; j < 2; ++j) {
      short8 kv = kp[j];
#pragma unroll
      for (int e = 0; e < 8; ++e) su = fmaf(qf[j * 8 + e], bf2f((u16)kv[e]), su);
    }
    s[5] = su;
  }
  {
    float su = 0.f;
    const float4* rp = reinterpret_cast<const float4*>(rk + rbase);
#pragma unroll
    for (int j = 0; j < 4; ++j) {
      float4 r4 = rp[j];
      su = fmaf(qf[j * 4 + 0], r4.x, su);
      su = fmaf(qf[j * 4 + 1], r4.y, su);
      su = fmaf(qf[j * 4 + 2], r4.z, su);
      su = fmaf(qf[j * 4 + 3], r4.w, su);
    }
    s[6] = su;
  }
#pragma unroll
  for (int u = 0; u < 7; ++u) {
    s[u] += __shfl_xor(s[u], 1);
    s[u] += __shfl_xor(s[u], 2);
  }
  float m = -1e30f;
#pragma unroll
  for (int u = 0; u < 7; ++u) {
    s[u] *= 0.125f;
    m = fmaxf(m, s[u]);
  }
  float e[7], tot = 0.f;
#pragma unroll
  for (int u = 0; u < 7; ++u) {
    e[u] = expf(s[u] - m);
    tot += e[u];
  }
  float inv = 1.f / tot;
#pragma unroll
  for (int u = 0; u < 7; ++u) e[u] *= inv;

  float av[16];
  {
    const float4* rp = reinterpret_cast<const float4*>(rv + rbase);
#pragma unroll
    for (int j = 0; j < 4; ++j) {
      float4 r4 = rp[j];
      av[j * 4 + 0] = e[6] * r4.x;
      av[j * 4 + 1] = e[6] * r4.y;
      av[j * 4 + 2] = e[6] * r4.z;
      av[j * 4 + 3] = e[6] * r4.w;
    }
  }
  {
    const short8* vp = reinterpret_cast<const short8*>(ve + row);
#pragma unroll
    for (int j = 0; j < 2; ++j) {
      short8 vvv = vp[j];
#pragma unroll
      for (int ee = 0; ee < 8; ++ee) av[j * 8 + ee] = fmaf(e[5], bf2f((u16)vvv[ee]), av[j * 8 + ee]);
    }
  }
#pragma unroll
  for (int u = 0; u < 5; ++u) {
    int lk = l + u - 2;
    if (lk >= 0 && lk < L_) {
      const short8* vp = reinterpret_cast<const short8*>(
          v + ((size_t)(b * 1024 + lk)) * 1024 + head * 64 + dq * 16);
#pragma unroll
      for (int j = 0; j < 2; ++j) {
        short8 vvv = vp[j];
#pragma unroll
        for (int ee = 0; ee < 8; ++ee) av[j * 8 + ee] = fmaf(e[u], bf2f((u16)vvv[ee]), av[j * 8 + ee]);
      }
    }
  }
  u16 ob[16];
#pragma unroll
  for (int j = 0; j < 16; ++j) ob[j] = f2bf(av[j]);
  uint4* d4 = reinterpret_cast<uint4*>(attbf + row);
  const uint4* s4 = reinterpret_cast<const uint4*>(ob);
  d4[0] = s4[0];
  d4[1] = s4[1];
}

// ---------- msa2 partial: block = (n, chunk, b); unnormalized sums (v = k) ----------
__global__ __launch_bounds__(256) void k_msa2p(const float* __restrict__ rq,
                                               const float* __restrict__ kk,
                                               const int* __restrict__ mask,
                                               float* __restrict__ pw,
                                               float* __restrict__ pE) {
  int n = blockIdx.x, c = blockIdx.y, b = blockIdx.z;
  int tid = threadIdx.x;
  __shared__ float sq_[HD_];
  __shared__ float se[260];
  size_t rb = (size_t)(b * NH_ + n) * HD_;
  if (tid < HD_) sq_[tid] = rq[rb + tid];
  __syncthreads();
  const float* kb = kk + rb * (size_t)(L_ + 1);
  int p0 = c * 256;
  {
    int p = p0 + tid;
    float e;
    if (p > 0 && mask[b * L_ + p - 1] == 0) {
      e = 0.f;
    } else {
      float acc = 0.f;
      for (int d = 0; d < HD_; ++d) acc = fmaf(sq_[d], kb[(size_t)d * (L_ + 1) + p], acc);
      e = expf(acc * 0.125f);
    }
    se[tid] = e;
  }
  int nP = 256;
  if (c == 3) {
    nP = 257;
    if (tid == 0) {
      float e;
      if (mask[b * L_ + 1023] == 0) {
        e = 0.f;
      } else {
        float acc = 0.f;
        for (int d = 0; d < HD_; ++d) acc = fmaf(sq_[d], kb[(size_t)d * (L_ + 1) + 1024], acc);
        e = expf(acc * 0.125f);
      }
      se[256] = e;
    }
  }
  __syncthreads();
  int lane = tid & 63, w = tid >> 6;
  if (w == 0) {
    float E = 0.f;
    for (int i = lane; i < nP; i += 64) E += se[i];
#pragma unroll
    for (int off = 32; off; off >>= 1) E += __shfl_xor(E, off);
    if (lane == 0) pE[((size_t)(b * NH_ + n)) * 4 + c] = E;
  }
  for (int dd = 0; dd < 16; ++dd) {
    int d = w * 16 + dd;
    const float* kd = kb + (size_t)d * (L_ + 1) + p0;
    float a = 0.f;
    for (int i = lane; i < nP; i += 64) a = fmaf(se[i], kd[i], a);
#pragma unroll
    for (int off = 32; off; off >>= 1) a += __shfl_xor(a, off);
    if (lane == 0) pw[(((size_t)(b * NH_ + n)) * 4 + c) * HD_ + d] = a;
  }
}

// ---------- msa2 reduce ----------
__global__ void k_msa2r(const float* __restrict__ pw, const float* __restrict__ pE,
                        float* __restrict__ satt) {
  int i = blockIdx.x * 256 + threadIdx.x;  // B*NH*HD
  int bn = i >> 6, d = i & 63;
  float E = pE[bn * 4 + 0] + pE[bn * 4 + 1] + pE[bn * 4 + 2] + pE[bn * 4 + 3];
  float ws = pw[((size_t)bn * 4 + 0) * HD_ + d] + pw[((size_t)bn * 4 + 1) * HD_ + d] +
             pw[((size_t)bn * 4 + 2) * HD_ + d] + pw[((size_t)bn * 4 + 3) * HD_ + d];
  satt[i] = ws / E;
}

// ---------- final: out = pad ? 0 : nodes ----------
__global__ void k_final(const float* __restrict__ nodes, const int* __restrict__ mask,
                        float* __restrict__ out) {
  int i = blockIdx.x * 256 + threadIdx.x;
  int row = i >> 8;
  int b = row >> 10, l = row & 1023;
  float4 v = (mask[b * L_ + l] == 0) ? float4{0.f, 0.f, 0.f, 0.f}
                                     : reinterpret_cast<const float4*>(nodes)[i];
  reinterpret_cast<float4*>(out)[i] = v;
}

__global__ void k_copy_relay(const float* __restrict__ relay, float* __restrict__ out) {
  int i = blockIdx.x * 256 + threadIdx.x;
  out[i] = relay[i];
}

}  // namespace

extern "C" void kernel_launch(void* const* d_in, const int* in_sizes, int n_in,
                              void* d_out, int out_size, void* d_ws, size_t ws_size,
                              hipStream_t stream) {
  (void)in_sizes; (void)n_in; (void)out_size; (void)ws_size;
  const float* data = (const float*)d_in[0];
  const int* mask = (const int*)d_in[1];
  const float* ln_s = (const float*)d_in[2];
  const float* ln_b = (const float*)d_in[3];
  const float* rwq = (const float*)d_in[4];
  const float* rwq_b = (const float*)d_in[5];
  const float* rwk = (const float*)d_in[6];
  const float* rwk_b = (const float*)d_in[7];
  const float* rwv = (const float*)d_in[8];
  const float* rwv_b = (const float*)d_in[9];
  const float* rwo = (const float*)d_in[10];
  const float* rwo_b = (const float*)d_in[11];
  const float* swq = (const float*)d_in[12];
  const float* swq_b = (const float*)d_in[13];
  const float* swk = (const float*)d_in[14];
  const float* swk_b = (const float*)d_in[15];
  const float* swo = (const float*)d_in[16];
  const float* swo_b = (const float*)d_in[17];
  float* out = (float*)d_out;

  const size_t SZ = (size_t)B_ * ND_ * L_;  // 4M elements
  float* f = (float*)d_ws;
  float* nodes = f; f += SZ;                       // fp32 [B,L,H]
  float* kkb = f; f += (size_t)B_ * ND_ * (L_ + 1);
  float* part = f; f += (size_t)B_ * 8 * H_;
  float* relay = f; f += B_ * H_;
  float* rk = f; f += B_ * ND_;
  float* rv = f; f += B_ * ND_;
  float* rq = f; f += B_ * ND_;
  float* satt = f; f += B_ * ND_;
  float* pw = f; f += (size_t)B_ * NH_ * 4 * HD_;
  float* pE = f; f += B_ * NH_ * 4;
  u16* u = (u16*)f;
  u16* xn_bf = u; u += SZ;       // [B,L,H]
  u16* embs_bf = u; u += SZ;     // [B,L,H]
  u16* att_bf = u; u += SZ;      // [B,L,ND]
  u16* nodes_bf = u; u += SZ;    // [B,L,H]
  u16* qkv5_bf = u; u += 5 * SZ; // [5][B,L,ND]: q,k,v,ke,ve
  u16* wq_bf = u; u += SZ;
  u16* wk_bf = u; u += SZ;
  u16* wv_bf = u; u += SZ;
  u16* wo_bf = u; u += SZ;
  u16* swk_bf = u; u += SZ;

  k_prep<<<dim3(4096, 7), 256, 0, stream>>>(data, rwq, rwk, rwv, rwo, swk,
                                            embs_bf, wq_bf, wk_bf, wv_bf, wo_bf, swk_bf, nodes);
  k_relay_part<<<dim3(H_ / 256, 8, B_), 256, 0, stream>>>(data, part);
  k_relay_reduce<<<dim3((B_ * H_) / 256), 256, 0, stream>>>(part, relay);

  for (int i = 0; i < ITERS_; ++i) {
    const u16* wq_i = wq_bf + (size_t)i * ND_ * H_;
    const u16* wk_i = wk_bf + (size_t)i * ND_ * H_;
    const u16* wv_i = wv_bf + (size_t)i * ND_ * H_;
    const u16* wo_i = wo_bf + (size_t)i * H_ * ND_;
    const u16* sk_i = swk_bf + (size_t)i * ND_ * H_;

    k_layernorm_bf<<<dim3(B_ * L_ / 4), 256, 0, stream>>>(nodes, ln_s + i * H_, ln_b + i * H_,
                                                          mask, xn_bf, i > 0 ? 1 : 0);
    k_gemm5<<<dim3(32, 40), 256, 0, stream>>>(wq_i, wk_i, wv_i,
                                              rwq_b + i * ND_, rwk_b + i * ND_, rwv_b + i * ND_,
                                              xn_bf, embs_bf, qkv5_bf);
    k_matvec2<<<dim3(256, B_, 2), 256, 0, stream>>>(
        rwk + (size_t)i * ND_ * H_, rwk_b + i * ND_, rk, ND_, 1,
        rwv + (size_t)i * ND_ * H_, rwv_b + i * ND_, rv, ND_, 1, relay);
    k_msa1<<<dim3(L_ / 4, 1, B_), 256, 0, stream>>>(qkv5_bf, qkv5_bf + SZ, qkv5_bf + 2 * SZ,
                                                    qkv5_bf + 3 * SZ, qkv5_bf + 4 * SZ, rk, rv, att_bf);
    k_gemm_wo<<<dim3(32, 8), 256, 0, stream>>>(wo_i, rwo_b + i * H_, att_bf, nodes, nodes_bf);
    // star attention (old relay; nodes before zeroing)
    k_matvec2<<<dim3(256, B_, 2), 256, 0, stream>>>(
        swq + (size_t)i * ND_ * H_, swq_b + i * ND_, rq, ND_, 1,
        swk + (size_t)i * ND_ * H_, swk_b + i * ND_, kkb, (long)ND_ * (L_ + 1), L_ + 1, relay);
    k_gemm_kkb<<<dim3(32, 8), 256, 0, stream>>>(sk_i, swk_b + i * ND_, nodes_bf, kkb);
    k_msa2p<<<dim3(NH_, 4, B_), 256, 0, stream>>>(rq, kkb, mask, pw, pE);
    k_msa2r<<<dim3((B_ * NH_ * HD_) / 256), 256, 0, stream>>>(pw, pE, satt);
    k_matvec<<<dim3(256, B_), 256, 0, stream>>>(swo + (size_t)i * H_ * ND_, swo_b + i * H_,
                                                satt, relay, 1);
  }
  k_final<<<4096, 256, 0, stream>>>(nodes, mask, out);
  k_copy_relay<<<dim3((B_ * H_) / 256), 256, 0, stream>>>(relay, out + (size_t)B_ * L_ * H_);
}

// Round 10
// 631.897 us; speedup vs baseline: 1.4033x; 1.1263x over previous
//
#include <hip/hip_runtime.h>
#include <math.h>

namespace {

constexpr int B_ = 4, L_ = 1024, H_ = 1024, NH_ = 16, HD_ = 64, ND_ = 1024, ITERS_ = 4;

typedef unsigned short u16;
typedef __attribute__((ext_vector_type(8))) short short8;
typedef __attribute__((ext_vector_type(4))) float f32x4;

__device__ inline u16 f2bf(float f) {
  unsigned u = __builtin_bit_cast(unsigned, f);
  u += 0x7FFFu + ((u >> 16) & 1u);
  return (u16)(u >> 16);
}
__device__ inline float bf2f(u16 v) {
  unsigned u = ((unsigned)v) << 16;
  return __builtin_bit_cast(float, u);
}

__device__ inline void gl_lds16(const u16* g, u16* l) {
  __builtin_amdgcn_global_load_lds((const __attribute__((address_space(1))) void*)g,
                                   (__attribute__((address_space(3))) void*)l, 16, 0, 0);
}

// ---------- prep: 6 f2bf conversions + nodes copy ----------
__global__ void k_prep(const float* __restrict__ data, const float* __restrict__ rwq,
                       const float* __restrict__ rwk, const float* __restrict__ rwv,
                       const float* __restrict__ rwo, const float* __restrict__ swk,
                       u16* __restrict__ embs_bf, u16* __restrict__ wq_bf,
                       u16* __restrict__ wk_bf, u16* __restrict__ wv_bf,
                       u16* __restrict__ wo_bf, u16* __restrict__ swk_bf,
                       float* __restrict__ nodes) {
  int i = blockIdx.x * 256 + threadIdx.x;
  int which = blockIdx.y;
  if (which == 6) {
    reinterpret_cast<float4*>(nodes)[i] = reinterpret_cast<const float4*>(data)[i];
    return;
  }
  const float* src;
  u16* dst;
  switch (which) {
    case 0: src = data; dst = embs_bf; break;
    case 1: src = rwq; dst = wq_bf; break;
    case 2: src = rwk; dst = wk_bf; break;
    case 3: src = rwv; dst = wv_bf; break;
    case 4: src = rwo; dst = wo_bf; break;
    default: src = swk; dst = swk_bf; break;
  }
  float4 v = reinterpret_cast<const float4*>(src)[i];
  ushort4 o;
  o.x = f2bf(v.x); o.y = f2bf(v.y); o.z = f2bf(v.z); o.w = f2bf(v.w);
  reinterpret_cast<ushort4*>(dst)[i] = o;
}

// ---------- relay init ----------
__global__ void k_relay_part(const float* __restrict__ data, float* __restrict__ part) {
  int b = blockIdx.z, chunk = blockIdx.y;
  int c = blockIdx.x * 256 + threadIdx.x;
  const float* p = data + ((size_t)b * L_ + chunk * 128) * H_ + c;
  float acc = 0.f;
  for (int l = 0; l < 128; ++l) acc += p[(size_t)l * H_];
  part[((size_t)b * 8 + chunk) * H_ + c] = acc;
}
__global__ void k_relay_reduce(const float* __restrict__ part, float* __restrict__ relay) {
  int i = blockIdx.x * 256 + threadIdx.x;
  int b = i >> 10, c = i & 1023;
  float acc = 0.f;
  for (int j = 0; j < 8; ++j) acc += part[((size_t)b * 8 + j) * H_ + c];
  relay[i] = acc * (1.f / (float)L_);
}

// ---------- LayerNorm rows of nodes [B,L,H]; fused pad-row zeroing ----------
__global__ __launch_bounds__(256) void k_layernorm_bf(float* __restrict__ nodes,
                                                      const float* __restrict__ s,
                                                      const float* __restrict__ bb,
                                                      const int* __restrict__ mask,
                                                      u16* __restrict__ y, int do_zero) {
  int row = blockIdx.x * 4 + (threadIdx.x >> 6);
  int lane = threadIdx.x & 63;
  int b = row >> 10, l = row & 1023;
  bool pad = do_zero && (mask[b * L_ + l] == 0);
  float4* xr = reinterpret_cast<float4*>(nodes + (size_t)row * H_);
  float4 v[4];
  float sum = 0.f, sq = 0.f;
#pragma unroll
  for (int j = 0; j < 4; ++j) {
    v[j] = pad ? float4{0.f, 0.f, 0.f, 0.f} : xr[lane + 64 * j];
    sum += v[j].x + v[j].y + v[j].z + v[j].w;
    sq += v[j].x * v[j].x + v[j].y * v[j].y + v[j].z * v[j].z + v[j].w * v[j].w;
  }
  if (pad) {
#pragma unroll
    for (int j = 0; j < 4; ++j) xr[lane + 64 * j] = float4{0.f, 0.f, 0.f, 0.f};
  }
#pragma unroll
  for (int off = 32; off; off >>= 1) {
    sum += __shfl_xor(sum, off);
    sq += __shfl_xor(sq, off);
  }
  float mu = sum * (1.f / (float)H_);
  float rstd = rsqrtf(sq * (1.f / (float)H_) - mu * mu + 1e-5f);
  ushort4* yr = reinterpret_cast<ushort4*>(y + (size_t)row * H_);
#pragma unroll
  for (int j = 0; j < 4; ++j) {
    int c4 = lane + 64 * j;
    float4 sc = reinterpret_cast<const float4*>(s)[c4];
    float4 bc = reinterpret_cast<const float4*>(bb)[c4];
    ushort4 o;
    o.x = f2bf((v[j].x - mu) * rstd * sc.x + bc.x);
    o.y = f2bf((v[j].y - mu) * rstd * sc.y + bc.y);
    o.z = f2bf((v[j].z - mu) * rstd * sc.z + bc.z);
    o.w = f2bf((v[j].w - mu) * rstd * sc.w + bc.w);
    yr[c4] = o;
  }
}

// ================= 128x128 MFMA GEMM, BK=64 (gemm5) =================

#define GEMM_PROLOGUE(XPTR, WPTR)                                              \
  __shared__ __align__(16) u16 sX[2][128 * 32];                                \
  __shared__ __align__(16) u16 sW[2][128 * 32];                                \
  const int t = threadIdx.x;                                                   \
  const int w = t >> 6, lane = t & 63;                                         \
  const int wm = w >> 1, wn = w & 1;                                           \
  const int r4 = lane >> 2, slot = lane & 3;                                   \
  const int rowS0 = w * 16 + r4, rowS1 = 64 + rowS0;                           \
  const int colS0 = ((slot ^ ((rowS0 >> 1) & 3)) << 3);                        \
  const int colS1 = ((slot ^ ((rowS1 >> 1) & 3)) << 3);                        \
  const u16* gX0 = (XPTR) + (size_t)(bm + rowS0) * 1024 + colS0;               \
  const u16* gX1 = (XPTR) + (size_t)(bm + rowS1) * 1024 + colS1;               \
  const u16* gW0 = (WPTR) + (size_t)(bn + rowS0) * 1024 + colS0;               \
  const u16* gW1 = (WPTR) + (size_t)(bn + rowS1) * 1024 + colS1;               \
  u16* lX0a = sX[0] + w * 512;                                                 \
  u16* lX0b = sX[1] + w * 512;                                                 \
  u16* lX1a = sX[0] + (4 + w) * 512;                                           \
  u16* lX1b = sX[1] + (4 + w) * 512;                                           \
  u16* lW0a = sW[0] + w * 512;                                                 \
  u16* lW0b = sW[1] + w * 512;                                                 \
  u16* lW1a = sW[0] + (4 + w) * 512;                                           \
  u16* lW1b = sW[1] + (4 + w) * 512;                                           \
  const int kidx = (((lane >> 4) ^ ((lane >> 1) & 3)) << 3);                   \
  f32x4 acc[4][4];                                                             \
  _Pragma("unroll") for (int i_ = 0; i_ < 4; ++i_)                             \
      _Pragma("unroll") for (int j_ = 0; j_ < 4; ++j_)                         \
          acc[i_][j_] = f32x4{0.f, 0.f, 0.f, 0.f};

#define GEMM_KLOOP64(AROWBASE, BROWBASE, ASRC, BSRC)                           \
  for (int ck = 0; ck < 1024; ck += 64) {                                      \
    gl_lds16(gX0, lX0a);                                                       \
    gl_lds16(gX0 + 32, lX0b);                                                  \
    gl_lds16(gX1, lX1a);                                                       \
    gl_lds16(gX1 + 32, lX1b);                                                  \
    gl_lds16(gW0, lW0a);                                                       \
    gl_lds16(gW0 + 32, lW0b);                                                  \
    gl_lds16(gW1, lW1a);                                                       \
    gl_lds16(gW1 + 32, lW1b);                                                  \
    gX0 += 64; gX1 += 64; gW0 += 64; gW1 += 64;                                \
    __syncthreads();                                                           \
    _Pragma("unroll") for (int h = 0; h < 2; ++h) {                            \
      short8 af_[4], bf_[4];                                                   \
      _Pragma("unroll") for (int mf = 0; mf < 4; ++mf)                         \
          af_[mf] = *reinterpret_cast<const short8*>(                          \
              &ASRC[h][((AROWBASE) + mf * 16) * 32 + kidx]);                   \
      _Pragma("unroll") for (int nf = 0; nf < 4; ++nf)                         \
          bf_[nf] = *reinterpret_cast<const short8*>(                          \
              &BSRC[h][((BROWBASE) + nf * 16) * 32 + kidx]);                   \
      _Pragma("unroll") for (int mf = 0; mf < 4; ++mf)                         \
          _Pragma("unroll") for (int nf = 0; nf < 4; ++nf)                     \
              acc[mf][nf] = __builtin_amdgcn_mfma_f32_16x16x32_bf16(           \
                  af_[mf], bf_[nf], acc[mf][nf], 0, 0, 0);                     \
    }                                                                          \
    __syncthreads();                                                          \
  }

// ---- 5-in-1 GEMM, swapped orientation (A=W -> M=o, B=X -> N=l(B*L)) ----
__global__ __launch_bounds__(256, 3) void k_gemm5(const u16* __restrict__ wq,
                                                  const u16* __restrict__ wk,
                                                  const u16* __restrict__ wv,
                                                  const float* __restrict__ bq,
                                                  const float* __restrict__ bk,
                                                  const float* __restrict__ bv,
                                                  const u16* __restrict__ xn,
                                                  const u16* __restrict__ embs,
                                                  u16* __restrict__ Y) {
  const int bm = blockIdx.x * 128;            // bl rows
  const int which = blockIdx.y >> 3;
  const int bn = (blockIdx.y & 7) * 128;      // o
  const u16* W = (which == 0) ? wq : ((which == 1 || which == 3) ? wk : wv);
  const float* bias = (which == 0) ? bq : ((which == 1 || which == 3) ? bk : bv);
  const u16* X = (which < 3) ? xn : embs;
  u16* Yw = Y + (size_t)which * ((size_t)B_ * L_ * ND_);

  GEMM_PROLOGUE(X, W)
  const int rW = wm * 64 + (lane & 15);
  const int rX = wn * 64 + (lane & 15);
  GEMM_KLOOP64(rW, rX, sW, sX)

#pragma unroll
  for (int mo = 0; mo < 4; ++mo) {
    int o0 = bn + wm * 64 + mo * 16 + ((lane >> 4) << 2);
    float4 bs = *reinterpret_cast<const float4*>(bias + o0);
#pragma unroll
    for (int nl = 0; nl < 4; ++nl) {
      int bl = bm + wn * 64 + nl * 16 + (lane & 15);
      f32x4 vv = acc[mo][nl];
      ushort4 ov;
      ov.x = f2bf(vv[0] + bs.x);
      ov.y = f2bf(vv[1] + bs.y);
      ov.z = f2bf(vv[2] + bs.z);
      ov.w = f2bf(vv[3] + bs.w);
      *reinterpret_cast<ushort4*>(&Yw[(size_t)bl * 1024 + o0]) = ov;
    }
  }
}

// ================= 64(o) x 128(bl) GEMM bodies (wo / kkb), BK=64 =================
// sW: 64 rows, sX: 128 rows. 512-block grids -> 2 blocks/CU.

#define SMALL_PROLOGUE(XPTR, WPTR)                                             \
  __shared__ __align__(16) u16 sX[2][128 * 32];                                \
  __shared__ __align__(16) u16 sW[2][64 * 32];                                 \
  const int t = threadIdx.x;                                                   \
  const int w = t >> 6, lane = t & 63;                                         \
  const int wm = w >> 1, wn = w & 1;                                           \
  const int r4 = lane >> 2, slot = lane & 3;                                   \
  const int rowS0 = w * 16 + r4, rowS1 = 64 + rowS0;                           \
  const int colS0 = ((slot ^ ((rowS0 >> 1) & 3)) << 3);                        \
  const int colS1 = ((slot ^ ((rowS1 >> 1) & 3)) << 3);                        \
  const u16* gX0 = (XPTR) + (size_t)(bm + rowS0) * 1024 + colS0;               \
  const u16* gX1 = (XPTR) + (size_t)(bm + rowS1) * 1024 + colS1;               \
  const u16* gW0 = (WPTR) + (size_t)(bn + rowS0) * 1024 + colS0;               \
  u16* lX0a = sX[0] + w * 512;                                                 \
  u16* lX0b = sX[1] + w * 512;                                                 \
  u16* lX1a = sX[0] + (4 + w) * 512;                                           \
  u16* lX1b = sX[1] + (4 + w) * 512;                                           \
  u16* lW0a = sW[0] + w * 512;                                                 \
  u16* lW0b = sW[1] + w * 512;                                                 \
  const int kidx = (((lane >> 4) ^ ((lane >> 1) & 3)) << 3);

#define SMALL_KLOOP(MFN, NFN, ACC, AROWBASE, BROWBASE, ASRC, BSRC)             \
  for (int ck = 0; ck < 1024; ck += 64) {                                      \
    gl_lds16(gX0, lX0a);                                                       \
    gl_lds16(gX0 + 32, lX0b);                                                  \
    gl_lds16(gX1, lX1a);                                                       \
    gl_lds16(gX1 + 32, lX1b);                                                  \
    gl_lds16(gW0, lW0a);                                                       \
    gl_lds16(gW0 + 32, lW0b);                                                  \
    gX0 += 64; gX1 += 64; gW0 += 64;                                           \
    __syncthreads();                                                           \
    _Pragma("unroll") for (int h = 0; h < 2; ++h) {                            \
      short8 af_[MFN], bf_[NFN];                                               \
      _Pragma("unroll") for (int mf = 0; mf < MFN; ++mf)                       \
          af_[mf] = *reinterpret_cast<const short8*>(                          \
              &ASRC[h][((AROWBASE) + mf * 16) * 32 + kidx]);                   \
      _Pragma("unroll") for (int nf = 0; nf < NFN; ++nf)                       \
          bf_[nf] = *reinterpret_cast<const short8*>(                          \
              &BSRC[h][((BROWBASE) + nf * 16) * 32 + kidx]);                   \
      _Pragma("unroll") for (int mf = 0; mf < MFN; ++mf)                       \
          _Pragma("unroll") for (int nf = 0; nf < NFN; ++nf)                   \
              ACC[mf][nf] = __builtin_amdgcn_mfma_f32_16x16x32_bf16(           \
                  af_[mf], bf_[nf], ACC[mf][nf], 0, 0, 0);                     \
    }                                                                          \
    __syncthreads();                                                          \
  }

// ---- Wo GEMM (swapped: A=W M=o 64, B=X N=bl 128); grid (32, 16) ----
__global__ __launch_bounds__(256, 2) void k_gemm_wo_s(const u16* __restrict__ W,
                                                      const float* __restrict__ bias,
                                                      const u16* __restrict__ X,
                                                      float* __restrict__ nodes,
                                                      u16* __restrict__ nodes_bf) {
  const int bm = blockIdx.x * 128;  // bl
  const int bn = blockIdx.y * 64;   // o
  SMALL_PROLOGUE(X, W)
  f32x4 acc[2][4];
#pragma unroll
  for (int i_ = 0; i_ < 2; ++i_)
#pragma unroll
    for (int j_ = 0; j_ < 4; ++j_) acc[i_][j_] = f32x4{0.f, 0.f, 0.f, 0.f};
  const int rW = wm * 32 + (lane & 15);
  const int rX = wn * 64 + (lane & 15);
  SMALL_KLOOP(2, 4, acc, rW, rX, sW, sX)

#pragma unroll
  for (int mo = 0; mo < 2; ++mo) {
    int o0 = bn + wm * 32 + mo * 16 + ((lane >> 4) << 2);
    float4 bs = *reinterpret_cast<const float4*>(bias + o0);
#pragma unroll
    for (int nl = 0; nl < 4; ++nl) {
      int bl = bm + wn * 64 + nl * 16 + (lane & 15);
      size_t ni = (size_t)bl * 1024 + o0;
      float4 curv = *reinterpret_cast<const float4*>(&nodes[ni]);
      f32x4 vv = acc[mo][nl];
      float r0 = vv[0] + bs.x; r0 = curv.x + (r0 > 0.f ? r0 : 0.01f * r0);
      float r1 = vv[1] + bs.y; r1 = curv.y + (r1 > 0.f ? r1 : 0.01f * r1);
      float r2 = vv[2] + bs.z; r2 = curv.z + (r2 > 0.f ? r2 : 0.01f * r2);
      float r3 = vv[3] + bs.w; r3 = curv.w + (r3 > 0.f ? r3 : 0.01f * r3);
      *reinterpret_cast<float4*>(&nodes[ni]) = float4{r0, r1, r2, r3};
      ushort4 ov;
      ov.x = f2bf(r0); ov.y = f2bf(r1); ov.z = f2bf(r2); ov.w = f2bf(r3);
      *reinterpret_cast<ushort4*>(&nodes_bf[ni]) = ov;
    }
  }
}

// ---- kkb GEMM (original: A=X M=bl 128, B=W N=o 64); out fp32 [b][o][1+l]; grid (32,16) ----
__global__ __launch_bounds__(256, 2) void k_gemm_kkb_s(const u16* __restrict__ W,
                                                       const float* __restrict__ bias,
                                                       const u16* __restrict__ X,
                                                       float* __restrict__ Y) {
  const int bm = blockIdx.x * 128;  // bl
  const int bn = blockIdx.y * 64;   // o
  SMALL_PROLOGUE(X, W)
  f32x4 acc[4][2];
#pragma unroll
  for (int i_ = 0; i_ < 4; ++i_)
#pragma unroll
    for (int j_ = 0; j_ < 2; ++j_) acc[i_][j_] = f32x4{0.f, 0.f, 0.f, 0.f};
  const int rX = wm * 64 + (lane & 15);
  const int rW = wn * 32 + (lane & 15);
  SMALL_KLOOP(4, 2, acc, rX, rW, sX, sW)

#pragma unroll
  for (int nf = 0; nf < 2; ++nf) {
    int o = bn + wn * 32 + nf * 16 + (lane & 15);
    float bs = bias[o];
#pragma unroll
    for (int mf = 0; mf < 4; ++mf) {
      int gl = bm + wm * 64 + mf * 16 + ((lane >> 4) << 2);
      int b = gl >> 10, l = gl & 1023;
      size_t yi = ((size_t)(b * 1024 + o)) * (size_t)(L_ + 1) + 1 + l;
      f32x4 v = acc[mf][nf];
#pragma unroll
      for (int r = 0; r < 4; ++r) Y[yi + r] = v[r] + bs;
    }
  }
}

// ---------- quad matvec: all 4 relay-consumers in one dispatch ----------
// z=0: rk, z=1: rv, z=2: rq, z=3: kkb col 0 (strided).
__global__ __launch_bounds__(256) void k_matvec4(const float* __restrict__ W0,
                                                 const float* __restrict__ b0, float* __restrict__ y0,
                                                 const float* __restrict__ W1,
                                                 const float* __restrict__ b1, float* __restrict__ y1,
                                                 const float* __restrict__ W2,
                                                 const float* __restrict__ b2, float* __restrict__ y2,
                                                 const float* __restrict__ W3,
                                                 const float* __restrict__ b3, float* __restrict__ y3,
                                                 long sB3, long sO3,
                                                 const float* __restrict__ x) {
  int b = blockIdx.y, z = blockIdx.z;
  const float* W = (z == 0) ? W0 : (z == 1) ? W1 : (z == 2) ? W2 : W3;
  const float* bias = (z == 0) ? b0 : (z == 1) ? b1 : (z == 2) ? b2 : b3;
  int o = blockIdx.x * 4 + (threadIdx.x >> 6);
  int lane = threadIdx.x & 63;
  const float* wr = W + (size_t)o * 1024;
  const float* xb = x + (size_t)b * 1024;
  float acc = 0.f;
  for (int c = lane; c < 1024; c += 64) acc += wr[c] * xb[c];
#pragma unroll
  for (int off = 32; off; off >>= 1) acc += __shfl_xor(acc, off);
  if (lane == 0) {
    acc += bias[o];
    if (z == 3) y3[(size_t)b * sB3 + (size_t)o * sO3] = acc;
    else if (z == 2) y2[(size_t)b * 1024 + o] = acc;
    else if (z == 1) y1[(size_t)b * 1024 + o] = acc;
    else y0[(size_t)b * 1024 + o] = acc;
  }
}

// ---------- msa1 ring attention: 16 d per thread, 4 l per block ----------
__global__ __launch_bounds__(256) void k_msa1(const u16* __restrict__ q,
                                              const u16* __restrict__ k,
                                              const u16* __restrict__ v,
                                              const u16* __restrict__ ke,
                                              const u16* __restrict__ ve,
                                              const float* __restrict__ rk,
                                              const float* __restrict__ rv,
                                              u16* __restrict__ attbf) {
  int t = threadIdx.x;
  int wv = t >> 6, lane = t & 63;
  int head = lane >> 2, dq = lane & 3;
  int l = blockIdx.x * 4 + wv;
  int b = blockIdx.z;
  size_t row = ((size_t)(b * 1024 + l)) * 1024 + head * 64 + dq * 16;
  size_t rbase = (size_t)b * 1024 + head * 64 + dq * 16;

  float qf[16];
  {
    const short8* qp = reinterpret_cast<const short8*>(q + row);
#pragma unroll
    for (int j = 0; j < 2; ++j) {
      short8 qv = qp[j];
#pragma unroll
      for (int e = 0; e < 8; ++e) qf[j * 8 + e] = bf2f((u16)qv[e]);
    }
  }
  float s[7];
#pragma unroll
  for (int u = 0; u < 5; ++u) {
    int lk = l + u - 2;
    float su = 0.f;
    if (lk >= 0 && lk < L_) {
      const short8* kp = reinterpret_cast<const short8*>(
          k + ((size_t)(b * 1024 + lk)) * 1024 + head * 64 + dq * 16);
#pragma unroll
      for (int j = 0; j < 2; ++j) {
        short8 kv = kp[j];
#pragma unroll
        for (int e = 0; e < 8; ++e) su = fmaf(qf[j * 8 + e], bf2f((u16)kv[e]), su);
      }
    }
    s[u] = su;
  }
  {
    float su = 0.f;
    const short8* kp = reinterpret_cast<const short8*>(ke + row);
#pragma unroll
    for (int j = 0; j < 2; ++j) {
      short8 kv = kp[j];
#pragma unroll
      for (int e = 0; e < 8; ++e) su = fmaf(qf[j * 8 + e], bf2f((u16)kv[e]), su);
    }
    s[5] = su;
  }
  {
    float su = 0.f;
    const float4* rp = reinterpret_cast<const float4*>(rk + rbase);
#pragma unroll
    for (int j = 0; j < 4; ++j) {
      float4 r4 = rp[j];
      su = fmaf(qf[j * 4 + 0], r4.x, su);
      su = fmaf(qf[j * 4 + 1], r4.y, su);
      su = fmaf(qf[j * 4 + 2], r4.z, su);
      su = fmaf(qf[j * 4 + 3], r4.w, su);
    }
    s[6] = su;
  }
#pragma unroll
  for (int u = 0; u < 7; ++u) {
    s[u] += __shfl_xor(s[u], 1);
    s[u] += __shfl_xor(s[u], 2);
  }
  float m = -1e30f;
#pragma unroll
  for (int u = 0; u < 7; ++u) {
    s[u] *= 0.125f;
    m = fmaxf(m, s[u]);
  }
  float e[7], tot = 0.f;
#pragma unroll
  for (int u = 0; u < 7; ++u) {
    e[u] = expf(s[u] - m);
    tot += e[u];
  }
  float inv = 1.f / tot;
#pragma unroll
  for (int u = 0; u < 7; ++u) e[u] *= inv;

  float av[16];
  {
    const float4* rp = reinterpret_cast<const float4*>(rv + rbase);
#pragma unroll
    for (int j = 0; j < 4; ++j) {
      float4 r4 = rp[j];
      av[j * 4 + 0] = e[6] * r4.x;
      av[j * 4 + 1] = e[6] * r4.y;
      av[j * 4 + 2] = e[6] * r4.z;
      av[j * 4 + 3] = e[6] * r4.w;
    }
  }
  {
    const short8* vp = reinterpret_cast<const short8*>(ve + row);
#pragma unroll
    for (int j = 0; j < 2; ++j) {
      short8 vvv = vp[j];
#pragma unroll
      for (int ee = 0; ee < 8; ++ee) av[j * 8 + ee] = fmaf(e[5], bf2f((u16)vvv[ee]), av[j * 8 + ee]);
    }
  }
#pragma unroll
  for (int u = 0; u < 5; ++u) {
    int lk = l + u - 2;
    if (lk >= 0 && lk < L_) {
      const short8* vp = reinterpret_cast<const short8*>(
          v + ((size_t)(b * 1024 + lk)) * 1024 + head * 64 + dq * 16);
#pragma unroll
      for (int j = 0; j < 2; ++j) {
        short8 vvv = vp[j];
#pragma unroll
        for (int ee = 0; ee < 8; ++ee) av[j * 8 + ee] = fmaf(e[u], bf2f((u16)vvv[ee]), av[j * 8 + ee]);
      }
    }
  }
  u16 ob[16];
#pragma unroll
  for (int j = 0; j < 16; ++j) ob[j] = f2bf(av[j]);
  uint4* d4 = reinterpret_cast<uint4*>(attbf + row);
  const uint4* s4 = reinterpret_cast<const uint4*>(ob);
  d4[0] = s4[0];
  d4[1] = s4[1];
}

// ---------- msa2 partial: block = (n, chunk, b); unnormalized sums (v = k) ----------
__global__ __launch_bounds__(256) void k_msa2p(const float* __restrict__ rq,
                                               const float* __restrict__ kk,
                                               const int* __restrict__ mask,
                                               float* __restrict__ pw,
                                               float* __restrict__ pE) {
  int n = blockIdx.x, c = blockIdx.y, b = blockIdx.z;
  int tid = threadIdx.x;
  __shared__ float sq_[HD_];
  __shared__ float se[260];
  size_t rb = (size_t)(b * NH_ + n) * HD_;
  if (tid < HD_) sq_[tid] = rq[rb + tid];
  __syncthreads();
  const float* kb = kk + rb * (size_t)(L_ + 1);
  int p0 = c * 256;
  {
    int p = p0 + tid;
    float e;
    if (p > 0 && mask[b * L_ + p - 1] == 0) {
      e = 0.f;
    } else {
      float acc = 0.f;
      for (int d = 0; d < HD_; ++d) acc = fmaf(sq_[d], kb[(size_t)d * (L_ + 1) + p], acc);
      e = expf(acc * 0.125f);
    }
    se[tid] = e;
  }
  int nP = 256;
  if (c == 3) {
    nP = 257;
    if (tid == 0) {
      float e;
      if (mask[b * L_ + 1023] == 0) {
        e = 0.f;
      } else {
        float acc = 0.f;
        for (int d = 0; d < HD_; ++d) acc = fmaf(sq_[d], kb[(size_t)d * (L_ + 1) + 1024], acc);
        e = expf(acc * 0.125f);
      }
      se[256] = e;
    }
  }
  __syncthreads();
  int lane = tid & 63, w = tid >> 6;
  if (w == 0) {
    float E = 0.f;
    for (int i = lane; i < nP; i += 64) E += se[i];
#pragma unroll
    for (int off = 32; off; off >>= 1) E += __shfl_xor(E, off);
    if (lane == 0) pE[((size_t)(b * NH_ + n)) * 4 + c] = E;
  }
  for (int dd = 0; dd < 16; ++dd) {
    int d = w * 16 + dd;
    const float* kd = kb + (size_t)d * (L_ + 1) + p0;
    float a = 0.f;
    for (int i = lane; i < nP; i += 64) a = fmaf(se[i], kd[i], a);
#pragma unroll
    for (int off = 32; off; off >>= 1) a += __shfl_xor(a, off);
    if (lane == 0) pw[(((size_t)(b * NH_ + n)) * 4 + c) * HD_ + d] = a;
  }
}

// ---------- fused msa2 reduce + swo matvec: relay = leaky(swo @ satt + bo) ----------
__global__ __launch_bounds__(256) void k_msa2r_swo(const float* __restrict__ pw,
                                                   const float* __restrict__ pE,
                                                   const float* __restrict__ swo,
                                                   const float* __restrict__ swo_b,
                                                   float* __restrict__ relay) {
  int b = blockIdx.y;
  int tid = threadIdx.x;
  __shared__ float satt[1024];
  // each thread computes 4 satt elements
#pragma unroll
  for (int j = 0; j < 4; ++j) {
    int idx = tid * 4 + j;
    int bn = b * 16 + (idx >> 6), d = idx & 63;
    float E = pE[bn * 4 + 0] + pE[bn * 4 + 1] + pE[bn * 4 + 2] + pE[bn * 4 + 3];
    float ws = pw[((size_t)bn * 4 + 0) * HD_ + d] + pw[((size_t)bn * 4 + 1) * HD_ + d] +
               pw[((size_t)bn * 4 + 2) * HD_ + d] + pw[((size_t)bn * 4 + 3) * HD_ + d];
    satt[idx] = ws / E;
  }
  __syncthreads();
  int o = blockIdx.x * 4 + (tid >> 6);
  int lane = tid & 63;
  const float* wr = swo + (size_t)o * 1024;
  float acc = 0.f;
  for (int c = lane; c < 1024; c += 64) acc = fmaf(wr[c], satt[c], acc);
#pragma unroll
  for (int off = 32; off; off >>= 1) acc += __shfl_xor(acc, off);
  if (lane == 0) {
    acc += swo_b[o];
    relay[(size_t)b * 1024 + o] = acc > 0.f ? acc : 0.01f * acc;
  }
}

// ---------- final: out = pad ? 0 : nodes ----------
__global__ void k_final(const float* __restrict__ nodes, const int* __restrict__ mask,
                        float* __restrict__ out) {
  int i = blockIdx.x * 256 + threadIdx.x;
  int row = i >> 8;
  int b = row >> 10, l = row & 1023;
  float4 v = (mask[b * L_ + l] == 0) ? float4{0.f, 0.f, 0.f, 0.f}
                                     : reinterpret_cast<const float4*>(nodes)[i];
  reinterpret_cast<float4*>(out)[i] = v;
}

__global__ void k_copy_relay(const float* __restrict__ relay, float* __restrict__ out) {
  int i = blockIdx.x * 256 + threadIdx.x;
  out[i] = relay[i];
}

}  // namespace

extern "C" void kernel_launch(void* const* d_in, const int* in_sizes, int n_in,
                              void* d_out, int out_size, void* d_ws, size_t ws_size,
                              hipStream_t stream) {
  (void)in_sizes; (void)n_in; (void)out_size; (void)ws_size;
  const float* data = (const float*)d_in[0];
  const int* mask = (const int*)d_in[1];
  const float* ln_s = (const float*)d_in[2];
  const float* ln_b = (const float*)d_in[3];
  const float* rwq = (const float*)d_in[4];
  const float* rwq_b = (const float*)d_in[5];
  const float* rwk = (const float*)d_in[6];
  const float* rwk_b = (const float*)d_in[7];
  const float* rwv = (const float*)d_in[8];
  const float* rwv_b = (const float*)d_in[9];
  const float* rwo = (const float*)d_in[10];
  const float* rwo_b = (const float*)d_in[11];
  const float* swq = (const float*)d_in[12];
  const float* swq_b = (const float*)d_in[13];
  const float* swk = (const float*)d_in[14];
  const float* swk_b = (const float*)d_in[15];
  const float* swo = (const float*)d_in[16];
  const float* swo_b = (const float*)d_in[17];
  float* out = (float*)d_out;

  const size_t SZ = (size_t)B_ * ND_ * L_;  // 4M elements
  float* f = (float*)d_ws;
  float* nodes = f; f += SZ;                       // fp32 [B,L,H]
  float* kkb = f; f += (size_t)B_ * ND_ * (L_ + 1);
  float* part = f; f += (size_t)B_ * 8 * H_;
  float* relay = f; f += B_ * H_;
  float* rk = f; f += B_ * ND_;
  float* rv = f; f += B_ * ND_;
  float* rq = f; f += B_ * ND_;
  float* pw = f; f += (size_t)B_ * NH_ * 4 * HD_;
  float* pE = f; f += B_ * NH_ * 4;
  u16* u = (u16*)f;
  u16* xn_bf = u; u += SZ;       // [B,L,H]
  u16* embs_bf = u; u += SZ;     // [B,L,H]
  u16* att_bf = u; u += SZ;      // [B,L,ND]
  u16* nodes_bf = u; u += SZ;    // [B,L,H]
  u16* qkv5_bf = u; u += 5 * SZ; // [5][B,L,ND]: q,k,v,ke,ve
  u16* wq_bf = u; u += SZ;
  u16* wk_bf = u; u += SZ;
  u16* wv_bf = u; u += SZ;
  u16* wo_bf = u; u += SZ;
  u16* swk_bf = u; u += SZ;

  k_prep<<<dim3(4096, 7), 256, 0, stream>>>(data, rwq, rwk, rwv, rwo, swk,
                                            embs_bf, wq_bf, wk_bf, wv_bf, wo_bf, swk_bf, nodes);
  k_relay_part<<<dim3(H_ / 256, 8, B_), 256, 0, stream>>>(data, part);
  k_relay_reduce<<<dim3((B_ * H_) / 256), 256, 0, stream>>>(part, relay);

  for (int i = 0; i < ITERS_; ++i) {
    const u16* wq_i = wq_bf + (size_t)i * ND_ * H_;
    const u16* wk_i = wk_bf + (size_t)i * ND_ * H_;
    const u16* wv_i = wv_bf + (size_t)i * ND_ * H_;
    const u16* wo_i = wo_bf + (size_t)i * H_ * ND_;
    const u16* sk_i = swk_bf + (size_t)i * ND_ * H_;

    k_layernorm_bf<<<dim3(B_ * L_ / 4), 256, 0, stream>>>(nodes, ln_s + i * H_, ln_b + i * H_,
                                                          mask, xn_bf, i > 0 ? 1 : 0);
    // all 4 relay-consuming matvecs (old relay): rk, rv, rq, kkb col0
    k_matvec4<<<dim3(256, B_, 4), 256, 0, stream>>>(
        rwk + (size_t)i * ND_ * H_, rwk_b + i * ND_, rk,
        rwv + (size_t)i * ND_ * H_, rwv_b + i * ND_, rv,
        swq + (size_t)i * ND_ * H_, swq_b + i * ND_, rq,
        swk + (size_t)i * ND_ * H_, swk_b + i * ND_, kkb, (long)ND_ * (L_ + 1), L_ + 1,
        relay);
    k_gemm5<<<dim3(32, 40), 256, 0, stream>>>(wq_i, wk_i, wv_i,
                                              rwq_b + i * ND_, rwk_b + i * ND_, rwv_b + i * ND_,
                                              xn_bf, embs_bf, qkv5_bf);
    k_msa1<<<dim3(L_ / 4, 1, B_), 256, 0, stream>>>(qkv5_bf, qkv5_bf + SZ, qkv5_bf + 2 * SZ,
                                                    qkv5_bf + 3 * SZ, qkv5_bf + 4 * SZ, rk, rv, att_bf);
    k_gemm_wo_s<<<dim3(32, 16), 256, 0, stream>>>(wo_i, rwo_b + i * H_, att_bf, nodes, nodes_bf);
    k_gemm_kkb_s<<<dim3(32, 16), 256, 0, stream>>>(sk_i, swk_b + i * ND_, nodes_bf, kkb);
    k_msa2p<<<dim3(NH_, 4, B_), 256, 0, stream>>>(rq, kkb, mask, pw, pE);
    k_msa2r_swo<<<dim3(256, B_), 256, 0, stream>>>(pw, pE, swo + (size_t)i * H_ * ND_,
                                                   swo_b + i * H_, relay);
  }
  k_final<<<4096, 256, 0, stream>>>(nodes, mask, out);
  k_copy_relay<<<dim3((B_ * H_) / 256), 256, 0, stream>>>(relay, out + (size_t)B_ * L_ * H_);
}

// Round 11
// 617.919 us; speedup vs baseline: 1.4351x; 1.0226x over previous
//
#include <hip/hip_runtime.h>
#include <math.h>

namespace {

constexpr int B_ = 4, L_ = 1024, H_ = 1024, NH_ = 16, HD_ = 64, ND_ = 1024, ITERS_ = 4;

typedef unsigned short u16;
typedef __attribute__((ext_vector_type(8))) short short8;
typedef __attribute__((ext_vector_type(4))) float f32x4;

__device__ inline u16 f2bf(float f) {
  unsigned u = __builtin_bit_cast(unsigned, f);
  u += 0x7FFFu + ((u >> 16) & 1u);
  return (u16)(u >> 16);
}
__device__ inline float bf2f(u16 v) {
  unsigned u = ((unsigned)v) << 16;
  return __builtin_bit_cast(float, u);
}

__device__ inline void gl_lds16(const u16* g, u16* l) {
  __builtin_amdgcn_global_load_lds((const __attribute__((address_space(1))) void*)g,
                                   (__attribute__((address_space(3))) void*)l, 16, 0, 0);
}

// ---------- prep: 6 f2bf conversions + nodes copy ----------
__global__ void k_prep(const float* __restrict__ data, const float* __restrict__ rwq,
                       const float* __restrict__ rwk, const float* __restrict__ rwv,
                       const float* __restrict__ rwo, const float* __restrict__ swk,
                       u16* __restrict__ embs_bf, u16* __restrict__ wq_bf,
                       u16* __restrict__ wk_bf, u16* __restrict__ wv_bf,
                       u16* __restrict__ wo_bf, u16* __restrict__ swk_bf,
                       float* __restrict__ nodes) {
  int i = blockIdx.x * 256 + threadIdx.x;
  int which = blockIdx.y;
  if (which == 6) {
    reinterpret_cast<float4*>(nodes)[i] = reinterpret_cast<const float4*>(data)[i];
    return;
  }
  const float* src;
  u16* dst;
  switch (which) {
    case 0: src = data; dst = embs_bf; break;
    case 1: src = rwq; dst = wq_bf; break;
    case 2: src = rwk; dst = wk_bf; break;
    case 3: src = rwv; dst = wv_bf; break;
    case 4: src = rwo; dst = wo_bf; break;
    default: src = swk; dst = swk_bf; break;
  }
  float4 v = reinterpret_cast<const float4*>(src)[i];
  ushort4 o;
  o.x = f2bf(v.x); o.y = f2bf(v.y); o.z = f2bf(v.z); o.w = f2bf(v.w);
  reinterpret_cast<ushort4*>(dst)[i] = o;
}

// ---------- relay init ----------
__global__ void k_relay_part(const float* __restrict__ data, float* __restrict__ part) {
  int b = blockIdx.z, chunk = blockIdx.y;
  int c = blockIdx.x * 256 + threadIdx.x;
  const float* p = data + ((size_t)b * L_ + chunk * 128) * H_ + c;
  float acc = 0.f;
  for (int l = 0; l < 128; ++l) acc += p[(size_t)l * H_];
  part[((size_t)b * 8 + chunk) * H_ + c] = acc;
}
__global__ void k_relay_reduce(const float* __restrict__ part, float* __restrict__ relay) {
  int i = blockIdx.x * 256 + threadIdx.x;
  int b = i >> 10, c = i & 1023;
  float acc = 0.f;
  for (int j = 0; j < 8; ++j) acc += part[((size_t)b * 8 + j) * H_ + c];
  relay[i] = acc * (1.f / (float)L_);
}

// ---------- LayerNorm rows of nodes [B,L,H]; fused pad-row zeroing ----------
__global__ __launch_bounds__(256) void k_layernorm_bf(float* __restrict__ nodes,
                                                      const float* __restrict__ s,
                                                      const float* __restrict__ bb,
                                                      const int* __restrict__ mask,
                                                      u16* __restrict__ y, int do_zero) {
  int row = blockIdx.x * 4 + (threadIdx.x >> 6);
  int lane = threadIdx.x & 63;
  int b = row >> 10, l = row & 1023;
  bool pad = do_zero && (mask[b * L_ + l] == 0);
  float4* xr = reinterpret_cast<float4*>(nodes + (size_t)row * H_);
  float4 v[4];
  float sum = 0.f, sq = 0.f;
#pragma unroll
  for (int j = 0; j < 4; ++j) {
    v[j] = pad ? float4{0.f, 0.f, 0.f, 0.f} : xr[lane + 64 * j];
    sum += v[j].x + v[j].y + v[j].z + v[j].w;
    sq += v[j].x * v[j].x + v[j].y * v[j].y + v[j].z * v[j].z + v[j].w * v[j].w;
  }
  if (pad) {
#pragma unroll
    for (int j = 0; j < 4; ++j) xr[lane + 64 * j] = float4{0.f, 0.f, 0.f, 0.f};
  }
#pragma unroll
  for (int off = 32; off; off >>= 1) {
    sum += __shfl_xor(sum, off);
    sq += __shfl_xor(sq, off);
  }
  float mu = sum * (1.f / (float)H_);
  float rstd = rsqrtf(sq * (1.f / (float)H_) - mu * mu + 1e-5f);
  ushort4* yr = reinterpret_cast<ushort4*>(y + (size_t)row * H_);
#pragma unroll
  for (int j = 0; j < 4; ++j) {
    int c4 = lane + 64 * j;
    float4 sc = reinterpret_cast<const float4*>(s)[c4];
    float4 bc = reinterpret_cast<const float4*>(bb)[c4];
    ushort4 o;
    o.x = f2bf((v[j].x - mu) * rstd * sc.x + bc.x);
    o.y = f2bf((v[j].y - mu) * rstd * sc.y + bc.y);
    o.z = f2bf((v[j].z - mu) * rstd * sc.z + bc.z);
    o.w = f2bf((v[j].w - mu) * rstd * sc.w + bc.w);
    yr[c4] = o;
  }
}

// ================= 128x128 MFMA GEMM, BK=64 (gemm5) =================

#define GEMM_PROLOGUE(XPTR, WPTR)                                              \
  __shared__ __align__(16) u16 sX[2][128 * 32];                                \
  __shared__ __align__(16) u16 sW[2][128 * 32];                                \
  const int t = threadIdx.x;                                                   \
  const int w = t >> 6, lane = t & 63;                                         \
  const int wm = w >> 1, wn = w & 1;                                           \
  const int r4 = lane >> 2, slot = lane & 3;                                   \
  const int rowS0 = w * 16 + r4, rowS1 = 64 + rowS0;                           \
  const int colS0 = ((slot ^ ((rowS0 >> 1) & 3)) << 3);                        \
  const int colS1 = ((slot ^ ((rowS1 >> 1) & 3)) << 3);                        \
  const u16* gX0 = (XPTR) + (size_t)(bm + rowS0) * 1024 + colS0;               \
  const u16* gX1 = (XPTR) + (size_t)(bm + rowS1) * 1024 + colS1;               \
  const u16* gW0 = (WPTR) + (size_t)(bn + rowS0) * 1024 + colS0;               \
  const u16* gW1 = (WPTR) + (size_t)(bn + rowS1) * 1024 + colS1;               \
  u16* lX0a = sX[0] + w * 512;                                                 \
  u16* lX0b = sX[1] + w * 512;                                                 \
  u16* lX1a = sX[0] + (4 + w) * 512;                                           \
  u16* lX1b = sX[1] + (4 + w) * 512;                                           \
  u16* lW0a = sW[0] + w * 512;                                                 \
  u16* lW0b = sW[1] + w * 512;                                                 \
  u16* lW1a = sW[0] + (4 + w) * 512;                                           \
  u16* lW1b = sW[1] + (4 + w) * 512;                                           \
  const int kidx = (((lane >> 4) ^ ((lane >> 1) & 3)) << 3);                   \
  f32x4 acc[4][4];                                                             \
  _Pragma("unroll") for (int i_ = 0; i_ < 4; ++i_)                             \
      _Pragma("unroll") for (int j_ = 0; j_ < 4; ++j_)                         \
          acc[i_][j_] = f32x4{0.f, 0.f, 0.f, 0.f};

#define GEMM_KLOOP64(AROWBASE, BROWBASE, ASRC, BSRC)                           \
  for (int ck = 0; ck < 1024; ck += 64) {                                      \
    gl_lds16(gX0, lX0a);                                                       \
    gl_lds16(gX0 + 32, lX0b);                                                  \
    gl_lds16(gX1, lX1a);                                                       \
    gl_lds16(gX1 + 32, lX1b);                                                  \
    gl_lds16(gW0, lW0a);                                                       \
    gl_lds16(gW0 + 32, lW0b);                                                  \
    gl_lds16(gW1, lW1a);                                                       \
    gl_lds16(gW1 + 32, lW1b);                                                  \
    gX0 += 64; gX1 += 64; gW0 += 64; gW1 += 64;                                \
    __syncthreads();                                                           \
    _Pragma("unroll") for (int h = 0; h < 2; ++h) {                            \
      short8 af_[4], bf_[4];                                                   \
      _Pragma("unroll") for (int mf = 0; mf < 4; ++mf)                         \
          af_[mf] = *reinterpret_cast<const short8*>(                          \
              &ASRC[h][((AROWBASE) + mf * 16) * 32 + kidx]);                   \
      _Pragma("unroll") for (int nf = 0; nf < 4; ++nf)                         \
          bf_[nf] = *reinterpret_cast<const short8*>(                          \
              &BSRC[h][((BROWBASE) + nf * 16) * 32 + kidx]);                   \
      _Pragma("unroll") for (int mf = 0; mf < 4; ++mf)                         \
          _Pragma("unroll") for (int nf = 0; nf < 4; ++nf)                     \
              acc[mf][nf] = __builtin_amdgcn_mfma_f32_16x16x32_bf16(           \
                  af_[mf], bf_[nf], acc[mf][nf], 0, 0, 0);                     \
    }                                                                          \
    __syncthreads();                                                          \
  }

// ---- 5-in-1 GEMM, swapped orientation (A=W -> M=o, B=X -> N=l(B*L)) ----
__global__ __launch_bounds__(256, 3) void k_gemm5(const u16* __restrict__ wq,
                                                  const u16* __restrict__ wk,
                                                  const u16* __restrict__ wv,
                                                  const float* __restrict__ bq,
                                                  const float* __restrict__ bk,
                                                  const float* __restrict__ bv,
                                                  const u16* __restrict__ xn,
                                                  const u16* __restrict__ embs,
                                                  u16* __restrict__ Y) {
  const int bm = blockIdx.x * 128;            // bl rows
  const int which = blockIdx.y >> 3;
  const int bn = (blockIdx.y & 7) * 128;      // o
  const u16* W = (which == 0) ? wq : ((which == 1 || which == 3) ? wk : wv);
  const float* bias = (which == 0) ? bq : ((which == 1 || which == 3) ? bk : bv);
  const u16* X = (which < 3) ? xn : embs;
  u16* Yw = Y + (size_t)which * ((size_t)B_ * L_ * ND_);

  GEMM_PROLOGUE(X, W)
  const int rW = wm * 64 + (lane & 15);
  const int rX = wn * 64 + (lane & 15);
  GEMM_KLOOP64(rW, rX, sW, sX)

#pragma unroll
  for (int mo = 0; mo < 4; ++mo) {
    int o0 = bn + wm * 64 + mo * 16 + ((lane >> 4) << 2);
    float4 bs = *reinterpret_cast<const float4*>(bias + o0);
#pragma unroll
    for (int nl = 0; nl < 4; ++nl) {
      int bl = bm + wn * 64 + nl * 16 + (lane & 15);
      f32x4 vv = acc[mo][nl];
      ushort4 ov;
      ov.x = f2bf(vv[0] + bs.x);
      ov.y = f2bf(vv[1] + bs.y);
      ov.z = f2bf(vv[2] + bs.z);
      ov.w = f2bf(vv[3] + bs.w);
      *reinterpret_cast<ushort4*>(&Yw[(size_t)bl * 1024 + o0]) = ov;
    }
  }
}

// ================= 64(o) x 128(bl) GEMM bodies (wo / kkb_sw), BK=64 =================

#define SMALL_PROLOGUE(XPTR, WPTR)                                             \
  __shared__ __align__(16) u16 sX[2][128 * 32];                                \
  __shared__ __align__(16) u16 sW[2][64 * 32];                                 \
  const int t = threadIdx.x;                                                   \
  const int w = t >> 6, lane = t & 63;                                         \
  const int wm = w >> 1, wn = w & 1;                                           \
  const int r4 = lane >> 2, slot = lane & 3;                                   \
  const int rowS0 = w * 16 + r4, rowS1 = 64 + rowS0;                           \
  const int colS0 = ((slot ^ ((rowS0 >> 1) & 3)) << 3);                        \
  const int colS1 = ((slot ^ ((rowS1 >> 1) & 3)) << 3);                        \
  const u16* gX0 = (XPTR) + (size_t)(bm + rowS0) * 1024 + colS0;               \
  const u16* gX1 = (XPTR) + (size_t)(bm + rowS1) * 1024 + colS1;               \
  const u16* gW0 = (WPTR) + (size_t)(bn + rowS0) * 1024 + colS0;               \
  u16* lX0a = sX[0] + w * 512;                                                 \
  u16* lX0b = sX[1] + w * 512;                                                 \
  u16* lX1a = sX[0] + (4 + w) * 512;                                           \
  u16* lX1b = sX[1] + (4 + w) * 512;                                           \
  u16* lW0a = sW[0] + w * 512;                                                 \
  u16* lW0b = sW[1] + w * 512;                                                 \
  const int kidx = (((lane >> 4) ^ ((lane >> 1) & 3)) << 3);

#define SMALL_KLOOP(MFN, NFN, ACC, AROWBASE, BROWBASE, ASRC, BSRC)             \
  for (int ck = 0; ck < 1024; ck += 64) {                                      \
    gl_lds16(gX0, lX0a);                                                       \
    gl_lds16(gX0 + 32, lX0b);                                                  \
    gl_lds16(gX1, lX1a);                                                       \
    gl_lds16(gX1 + 32, lX1b);                                                  \
    gl_lds16(gW0, lW0a);                                                       \
    gl_lds16(gW0 + 32, lW0b);                                                  \
    gX0 += 64; gX1 += 64; gW0 += 64;                                           \
    __syncthreads();                                                           \
    _Pragma("unroll") for (int h = 0; h < 2; ++h) {                            \
      short8 af_[MFN], bf_[NFN];                                               \
      _Pragma("unroll") for (int mf = 0; mf < MFN; ++mf)                       \
          af_[mf] = *reinterpret_cast<const short8*>(                          \
              &ASRC[h][((AROWBASE) + mf * 16) * 32 + kidx]);                   \
      _Pragma("unroll") for (int nf = 0; nf < NFN; ++nf)                       \
          bf_[nf] = *reinterpret_cast<const short8*>(                          \
              &BSRC[h][((BROWBASE) + nf * 16) * 32 + kidx]);                   \
      _Pragma("unroll") for (int mf = 0; mf < MFN; ++mf)                       \
          _Pragma("unroll") for (int nf = 0; nf < NFN; ++nf)                   \
              ACC[mf][nf] = __builtin_amdgcn_mfma_f32_16x16x32_bf16(           \
                  af_[mf], bf_[nf], ACC[mf][nf], 0, 0, 0);                     \
    }                                                                          \
    __syncthreads();                                                          \
  }

// ---- Wo GEMM (swapped: A=W M=o 64, B=X N=bl 128); grid (32, 16) ----
__global__ __launch_bounds__(256, 2) void k_gemm_wo_s(const u16* __restrict__ W,
                                                      const float* __restrict__ bias,
                                                      const u16* __restrict__ X,
                                                      float* __restrict__ nodes,
                                                      u16* __restrict__ nodes_bf) {
  const int bm = blockIdx.x * 128;  // bl
  const int bn = blockIdx.y * 64;   // o
  SMALL_PROLOGUE(X, W)
  f32x4 acc[2][4];
#pragma unroll
  for (int i_ = 0; i_ < 2; ++i_)
#pragma unroll
    for (int j_ = 0; j_ < 4; ++j_) acc[i_][j_] = f32x4{0.f, 0.f, 0.f, 0.f};
  const int rW = wm * 32 + (lane & 15);
  const int rX = wn * 64 + (lane & 15);
  SMALL_KLOOP(2, 4, acc, rW, rX, sW, sX)

#pragma unroll
  for (int mo = 0; mo < 2; ++mo) {
    int o0 = bn + wm * 32 + mo * 16 + ((lane >> 4) << 2);
    float4 bs = *reinterpret_cast<const float4*>(bias + o0);
#pragma unroll
    for (int nl = 0; nl < 4; ++nl) {
      int bl = bm + wn * 64 + nl * 16 + (lane & 15);
      size_t ni = (size_t)bl * 1024 + o0;
      float4 curv = *reinterpret_cast<const float4*>(&nodes[ni]);
      f32x4 vv = acc[mo][nl];
      float r0 = vv[0] + bs.x; r0 = curv.x + (r0 > 0.f ? r0 : 0.01f * r0);
      float r1 = vv[1] + bs.y; r1 = curv.y + (r1 > 0.f ? r1 : 0.01f * r1);
      float r2 = vv[2] + bs.z; r2 = curv.z + (r2 > 0.f ? r2 : 0.01f * r2);
      float r3 = vv[3] + bs.w; r3 = curv.w + (r3 > 0.f ? r3 : 0.01f * r3);
      *reinterpret_cast<float4*>(&nodes[ni]) = float4{r0, r1, r2, r3};
      ushort4 ov;
      ov.x = f2bf(r0); ov.y = f2bf(r1); ov.z = f2bf(r2); ov.w = f2bf(r3);
      *reinterpret_cast<ushort4*>(&nodes_bf[ni]) = ov;
    }
  }
}

// ---- kkb GEMM swapped: out bf16 [b][1+l][o]; grid (32, 16) ----
__global__ __launch_bounds__(256, 2) void k_gemm_kkb_sw(const u16* __restrict__ W,
                                                        const float* __restrict__ bias,
                                                        const u16* __restrict__ X,
                                                        u16* __restrict__ Y) {
  const int bm = blockIdx.x * 128;  // bl
  const int bn = blockIdx.y * 64;   // o
  SMALL_PROLOGUE(X, W)
  f32x4 acc[2][4];
#pragma unroll
  for (int i_ = 0; i_ < 2; ++i_)
#pragma unroll
    for (int j_ = 0; j_ < 4; ++j_) acc[i_][j_] = f32x4{0.f, 0.f, 0.f, 0.f};
  const int rW = wm * 32 + (lane & 15);
  const int rX = wn * 64 + (lane & 15);
  SMALL_KLOOP(2, 4, acc, rW, rX, sW, sX)

#pragma unroll
  for (int mo = 0; mo < 2; ++mo) {
    int o0 = bn + wm * 32 + mo * 16 + ((lane >> 4) << 2);
    float4 bs = *reinterpret_cast<const float4*>(bias + o0);
#pragma unroll
    for (int nl = 0; nl < 4; ++nl) {
      int bl = bm + wn * 64 + nl * 16 + (lane & 15);
      size_t row = (size_t)(bl >> 10) * 1025 + 1 + (bl & 1023);
      f32x4 vv = acc[mo][nl];
      ushort4 ov;
      ov.x = f2bf(vv[0] + bs.x);
      ov.y = f2bf(vv[1] + bs.y);
      ov.z = f2bf(vv[2] + bs.z);
      ov.w = f2bf(vv[3] + bs.w);
      *reinterpret_cast<ushort4*>(&Y[row * 1024 + o0]) = ov;
    }
  }
}

// ---------- quad matvec: rk, rv, rq (fp32) and kkb_sw row 0 (bf16) ----------
__global__ __launch_bounds__(256) void k_matvec4(const float* __restrict__ W0,
                                                 const float* __restrict__ b0, float* __restrict__ y0,
                                                 const float* __restrict__ W1,
                                                 const float* __restrict__ b1, float* __restrict__ y1,
                                                 const float* __restrict__ W2,
                                                 const float* __restrict__ b2, float* __restrict__ y2,
                                                 const float* __restrict__ W3,
                                                 const float* __restrict__ b3, u16* __restrict__ y3b,
                                                 const float* __restrict__ x) {
  int b = blockIdx.y, z = blockIdx.z;
  const float* W = (z == 0) ? W0 : (z == 1) ? W1 : (z == 2) ? W2 : W3;
  const float* bias = (z == 0) ? b0 : (z == 1) ? b1 : (z == 2) ? b2 : b3;
  int o = blockIdx.x * 4 + (threadIdx.x >> 6);
  int lane = threadIdx.x & 63;
  const float* wr = W + (size_t)o * 1024;
  const float* xb = x + (size_t)b * 1024;
  float acc = 0.f;
  for (int c = lane; c < 1024; c += 64) acc += wr[c] * xb[c];
#pragma unroll
  for (int off = 32; off; off >>= 1) acc += __shfl_xor(acc, off);
  if (lane == 0) {
    acc += bias[o];
    if (z == 3) y3b[(size_t)b * 1025 * 1024 + o] = f2bf(acc);
    else if (z == 2) y2[(size_t)b * 1024 + o] = acc;
    else if (z == 1) y1[(size_t)b * 1024 + o] = acc;
    else y0[(size_t)b * 1024 + o] = acc;
  }
}

// ---------- single matvec ----------
__global__ __launch_bounds__(256) void k_matvec(const float* __restrict__ W,
                                                const float* __restrict__ bias,
                                                const float* __restrict__ x,
                                                float* __restrict__ y, int leaky) {
  int b = blockIdx.y;
  int o = blockIdx.x * 4 + (threadIdx.x >> 6);
  int lane = threadIdx.x & 63;
  const float* wr = W + (size_t)o * 1024;
  const float* xb = x + (size_t)b * 1024;
  float acc = 0.f;
  for (int c = lane; c < 1024; c += 64) acc += wr[c] * xb[c];
#pragma unroll
  for (int off = 32; off; off >>= 1) acc += __shfl_xor(acc, off);
  if (lane == 0) {
    acc += bias[o];
    if (leaky) acc = acc > 0.f ? acc : 0.01f * acc;
    y[(size_t)b * 1024 + o] = acc;
  }
}

// ---------- msa1 ring attention: 16 d per thread, 4 l per block ----------
__global__ __launch_bounds__(256) void k_msa1(const u16* __restrict__ q,
                                              const u16* __restrict__ k,
                                              const u16* __restrict__ v,
                                              const u16* __restrict__ ke,
                                              const u16* __restrict__ ve,
                                              const float* __restrict__ rk,
                                              const float* __restrict__ rv,
                                              u16* __restrict__ attbf) {
  int t = threadIdx.x;
  int wv = t >> 6, lane = t & 63;
  int head = lane >> 2, dq = lane & 3;
  int l = blockIdx.x * 4 + wv;
  int b = blockIdx.z;
  size_t row = ((size_t)(b * 1024 + l)) * 1024 + head * 64 + dq * 16;
  size_t rbase = (size_t)b * 1024 + head * 64 + dq * 16;

  float qf[16];
  {
    const short8* qp = reinterpret_cast<const short8*>(q + row);
#pragma unroll
    for (int j = 0; j < 2; ++j) {
      short8 qv = qp[j];
#pragma unroll
      for (int e = 0; e < 8; ++e) qf[j * 8 + e] = bf2f((u16)qv[e]);
    }
  }
  float s[7];
#pragma unroll
  for (int u = 0; u < 5; ++u) {
    int lk = l + u - 2;
    float su = 0.f;
    if (lk >= 0 && lk < L_) {
      const short8* kp = reinterpret_cast<const short8*>(
          k + ((size_t)(b * 1024 + lk)) * 1024 + head * 64 + dq * 16);
#pragma unroll
      for (int j = 0; j < 2; ++j) {
        short8 kv = kp[j];
#pragma unroll
        for (int e = 0; e < 8; ++e) su = fmaf(qf[j * 8 + e], bf2f((u16)kv[e]), su);
      }
    }
    s[u] = su;
  }
  {
    float su = 0.f;
    const short8* kp = reinterpret_cast<const short8*>(ke + row);
#pragma unroll
    for (int j = 0; j < 2; ++j) {
      short8 kv = kp[j];
#pragma unroll
      for (int e = 0; e < 8; ++e) su = fmaf(qf[j * 8 + e], bf2f((u16)kv[e]), su);
    }
    s[5] = su;
  }
  {
    float su = 0.f;
    const float4* rp = reinterpret_cast<const float4*>(rk + rbase);
#pragma unroll
    for (int j = 0; j < 4; ++j) {
      float4 r4 = rp[j];
      su = fmaf(qf[j * 4 + 0], r4.x, su);
      su = fmaf(qf[j * 4 + 1], r4.y, su);
      su = fmaf(qf[j * 4 + 2], r4.z, su);
      su = fmaf(qf[j * 4 + 3], r4.w, su);
    }
    s[6] = su;
  }
#pragma unroll
  for (int u = 0; u < 7; ++u) {
    s[u] += __shfl_xor(s[u], 1);
    s[u] += __shfl_xor(s[u], 2);
  }
  float m = -1e30f;
#pragma unroll
  for (int u = 0; u < 7; ++u) {
    s[u] *= 0.125f;
    m = fmaxf(m, s[u]);
  }
  float e[7], tot = 0.f;
#pragma unroll
  for (int u = 0; u < 7; ++u) {
    e[u] = expf(s[u] - m);
    tot += e[u];
  }
  float inv = 1.f / tot;
#pragma unroll
  for (int u = 0; u < 7; ++u) e[u] *= inv;

  float av[16];
  {
    const float4* rp = reinterpret_cast<const float4*>(rv + rbase);
#pragma unroll
    for (int j = 0; j < 4; ++j) {
      float4 r4 = rp[j];
      av[j * 4 + 0] = e[6] * r4.x;
      av[j * 4 + 1] = e[6] * r4.y;
      av[j * 4 + 2] = e[6] * r4.z;
      av[j * 4 + 3] = e[6] * r4.w;
    }
  }
  {
    const short8* vp = reinterpret_cast<const short8*>(ve + row);
#pragma unroll
    for (int j = 0; j < 2; ++j) {
      short8 vvv = vp[j];
#pragma unroll
      for (int ee = 0; ee < 8; ++ee) av[j * 8 + ee] = fmaf(e[5], bf2f((u16)vvv[ee]), av[j * 8 + ee]);
    }
  }
#pragma unroll
  for (int u = 0; u < 5; ++u) {
    int lk = l + u - 2;
    if (lk >= 0 && lk < L_) {
      const short8* vp = reinterpret_cast<const short8*>(
          v + ((size_t)(b * 1024 + lk)) * 1024 + head * 64 + dq * 16);
#pragma unroll
      for (int j = 0; j < 2; ++j) {
        short8 vvv = vp[j];
#pragma unroll
        for (int ee = 0; ee < 8; ++ee) av[j * 8 + ee] = fmaf(e[u], bf2f((u16)vvv[ee]), av[j * 8 + ee]);
      }
    }
  }
  u16 ob[16];
#pragma unroll
  for (int j = 0; j < 16; ++j) ob[j] = f2bf(av[j]);
  uint4* d4 = reinterpret_cast<uint4*>(attbf + row);
  const uint4* s4 = reinterpret_cast<const uint4*>(ob);
  d4[0] = s4[0];
  d4[1] = s4[1];
}

// ---------- msa2 flash-style: wave per 16-position chunk (v = k, faithful) ----------
// kkb bf16 [b][p][o]. Per wave: for each p, 16-ch dot vs rq (registers),
// 4-lane reduce, e = exp(s/8) (no max — consistent with prior rounds),
// av[16] += e*k, E += e. 68 deterministic wave-chunk partials.
__global__ __launch_bounds__(256) void k_msa2f(const u16* __restrict__ kkb,
                                               const float* __restrict__ rq,
                                               const int* __restrict__ mask,
                                               float* __restrict__ avp,
                                               float* __restrict__ Ep) {
  int b = blockIdx.y;
  int w = threadIdx.x >> 6, lane = threadIdx.x & 63;
  int wc = blockIdx.x * 4 + w;  // 0..67
  int q4 = lane & 3;
  int ch0 = lane * 16;
  float rqv[16];
  {
    const float4* rp = reinterpret_cast<const float4*>(rq + (size_t)b * 1024 + ch0);
#pragma unroll
    for (int j = 0; j < 4; ++j) {
      float4 v4 = rp[j];
      rqv[j * 4 + 0] = v4.x; rqv[j * 4 + 1] = v4.y;
      rqv[j * 4 + 2] = v4.z; rqv[j * 4 + 3] = v4.w;
    }
  }
  float av[16];
#pragma unroll
  for (int j = 0; j < 16; ++j) av[j] = 0.f;
  float eacc = 0.f;
  int p0 = wc * 16;
  int pend = p0 + 16;
  if (pend > 1025) pend = 1025;
  for (int p = p0; p < pend; ++p) {
    if (p > 0 && mask[b * L_ + p - 1] == 0) continue;  // wave-uniform
    const uint4* kr = reinterpret_cast<const uint4*>(kkb + ((size_t)b * 1025 + p) * 1024 + ch0);
    uint4 ka = kr[0], kb2 = kr[1];
    float kf[16];
    const u16* kp = reinterpret_cast<const u16*>(&ka);
#pragma unroll
    for (int j = 0; j < 8; ++j) kf[j] = bf2f(kp[j]);
    const u16* kp2 = reinterpret_cast<const u16*>(&kb2);
#pragma unroll
    for (int j = 0; j < 8; ++j) kf[8 + j] = bf2f(kp2[j]);
    float s = 0.f;
#pragma unroll
    for (int j = 0; j < 16; ++j) s = fmaf(rqv[j], kf[j], s);
    s += __shfl_xor(s, 1);
    s += __shfl_xor(s, 2);
    float e = expf(s * 0.125f);
    if (q4 == 0) eacc += e;
#pragma unroll
    for (int j = 0; j < 16; ++j) av[j] = fmaf(e, kf[j], av[j]);
  }
  float* ap = avp + ((size_t)b * 68 + wc) * 1024 + ch0;
#pragma unroll
  for (int j = 0; j < 4; ++j)
    reinterpret_cast<float4*>(ap)[j] =
        float4{av[j * 4 + 0], av[j * 4 + 1], av[j * 4 + 2], av[j * 4 + 3]};
  if (q4 == 0) Ep[((size_t)b * 68 + wc) * 16 + (lane >> 2)] = eacc;
}

// ---------- msa2 reduce: satt = (sum avp) / (sum Ep) ----------
__global__ void k_msa2r(const float* __restrict__ avp, const float* __restrict__ Ep,
                        float* __restrict__ satt) {
  int b = blockIdx.y;
  int idx = blockIdx.x * 256 + threadIdx.x;  // 0..1023
  int head = idx >> 6;
  float a = 0.f, E = 0.f;
  for (int k = 0; k < 68; ++k) a += avp[((size_t)b * 68 + k) * 1024 + idx];
  for (int k = 0; k < 68; ++k) E += Ep[((size_t)b * 68 + k) * 16 + head];
  satt[(size_t)b * 1024 + idx] = a / E;
}

// ---------- final: out = pad ? 0 : nodes ----------
__global__ void k_final(const float* __restrict__ nodes, const int* __restrict__ mask,
                        float* __restrict__ out) {
  int i = blockIdx.x * 256 + threadIdx.x;
  int row = i >> 8;
  int b = row >> 10, l = row & 1023;
  float4 v = (mask[b * L_ + l] == 0) ? float4{0.f, 0.f, 0.f, 0.f}
                                     : reinterpret_cast<const float4*>(nodes)[i];
  reinterpret_cast<float4*>(out)[i] = v;
}

__global__ void k_copy_relay(const float* __restrict__ relay, float* __restrict__ out) {
  int i = blockIdx.x * 256 + threadIdx.x;
  out[i] = relay[i];
}

}  // namespace

extern "C" void kernel_launch(void* const* d_in, const int* in_sizes, int n_in,
                              void* d_out, int out_size, void* d_ws, size_t ws_size,
                              hipStream_t stream) {
  (void)in_sizes; (void)n_in; (void)out_size; (void)ws_size;
  const float* data = (const float*)d_in[0];
  const int* mask = (const int*)d_in[1];
  const float* ln_s = (const float*)d_in[2];
  const float* ln_b = (const float*)d_in[3];
  const float* rwq = (const float*)d_in[4];
  const float* rwq_b = (const float*)d_in[5];
  const float* rwk = (const float*)d_in[6];
  const float* rwk_b = (const float*)d_in[7];
  const float* rwv = (const float*)d_in[8];
  const float* rwv_b = (const float*)d_in[9];
  const float* rwo = (const float*)d_in[10];
  const float* rwo_b = (const float*)d_in[11];
  const float* swq = (const float*)d_in[12];
  const float* swq_b = (const float*)d_in[13];
  const float* swk = (const float*)d_in[14];
  const float* swk_b = (const float*)d_in[15];
  const float* swo = (const float*)d_in[16];
  const float* swo_b = (const float*)d_in[17];
  float* out = (float*)d_out;

  const size_t SZ = (size_t)B_ * ND_ * L_;  // 4M elements
  float* f = (float*)d_ws;
  float* nodes = f; f += SZ;                       // fp32 [B,L,H]
  float* part = f; f += (size_t)B_ * 8 * H_;
  float* relay = f; f += B_ * H_;
  float* rk = f; f += B_ * ND_;
  float* rv = f; f += B_ * ND_;
  float* rq = f; f += B_ * ND_;
  float* satt = f; f += B_ * ND_;
  float* avp = f; f += (size_t)B_ * 68 * 1024;
  float* Ep = f; f += (size_t)B_ * 68 * 16;
  u16* u = (u16*)f;
  u16* xn_bf = u; u += SZ;       // [B,L,H]
  u16* embs_bf = u; u += SZ;     // [B,L,H]
  u16* att_bf = u; u += SZ;      // [B,L,ND]
  u16* nodes_bf = u; u += SZ;    // [B,L,H]
  u16* kkb_sw = u; u += (size_t)B_ * 1025 * 1024;  // bf16 [b][p][o]
  u16* qkv5_bf = u; u += 5 * SZ; // [5][B,L,ND]: q,k,v,ke,ve
  u16* wq_bf = u; u += SZ;
  u16* wk_bf = u; u += SZ;
  u16* wv_bf = u; u += SZ;
  u16* wo_bf = u; u += SZ;
  u16* swk_bf = u; u += SZ;

  k_prep<<<dim3(4096, 7), 256, 0, stream>>>(data, rwq, rwk, rwv, rwo, swk,
                                            embs_bf, wq_bf, wk_bf, wv_bf, wo_bf, swk_bf, nodes);
  k_relay_part<<<dim3(H_ / 256, 8, B_), 256, 0, stream>>>(data, part);
  k_relay_reduce<<<dim3((B_ * H_) / 256), 256, 0, stream>>>(part, relay);

  for (int i = 0; i < ITERS_; ++i) {
    const u16* wq_i = wq_bf + (size_t)i * ND_ * H_;
    const u16* wk_i = wk_bf + (size_t)i * ND_ * H_;
    const u16* wv_i = wv_bf + (size_t)i * ND_ * H_;
    const u16* wo_i = wo_bf + (size_t)i * H_ * ND_;
    const u16* sk_i = swk_bf + (size_t)i * ND_ * H_;

    k_layernorm_bf<<<dim3(B_ * L_ / 4), 256, 0, stream>>>(nodes, ln_s + i * H_, ln_b + i * H_,
                                                          mask, xn_bf, i > 0 ? 1 : 0);
    // rk, rv, rq (fp32) + kkb_sw row 0 (bf16) — all read iteration-start relay
    k_matvec4<<<dim3(256, B_, 4), 256, 0, stream>>>(
        rwk + (size_t)i * ND_ * H_, rwk_b + i * ND_, rk,
        rwv + (size_t)i * ND_ * H_, rwv_b + i * ND_, rv,
        swq + (size_t)i * ND_ * H_, swq_b + i * ND_, rq,
        swk + (size_t)i * ND_ * H_, swk_b + i * ND_, kkb_sw, relay);
    k_gemm5<<<dim3(32, 40), 256, 0, stream>>>(wq_i, wk_i, wv_i,
                                              rwq_b + i * ND_, rwk_b + i * ND_, rwv_b + i * ND_,
                                              xn_bf, embs_bf, qkv5_bf);
    k_msa1<<<dim3(L_ / 4, 1, B_), 256, 0, stream>>>(qkv5_bf, qkv5_bf + SZ, qkv5_bf + 2 * SZ,
                                                    qkv5_bf + 3 * SZ, qkv5_bf + 4 * SZ, rk, rv, att_bf);
    k_gemm_wo_s<<<dim3(32, 16), 256, 0, stream>>>(wo_i, rwo_b + i * H_, att_bf, nodes, nodes_bf);
    k_gemm_kkb_sw<<<dim3(32, 16), 256, 0, stream>>>(sk_i, swk_b + i * ND_, nodes_bf, kkb_sw);
    k_msa2f<<<dim3(17, B_), 256, 0, stream>>>(kkb_sw, rq, mask, avp, Ep);
    k_msa2r<<<dim3(4, B_), 256, 0, stream>>>(avp, Ep, satt);
    k_matvec<<<dim3(256, B_), 256, 0, stream>>>(swo + (size_t)i * H_ * ND_, swo_b + i * H_,
                                                satt, relay, 1);
  }
  k_final<<<4096, 256, 0, stream>>>(nodes, mask, out);
  k_copy_relay<<<dim3((B_ * H_) / 256), 256, 0, stream>>>(relay, out + (size_t)B_ * L_ * H_);
}